// Round 1
// baseline (862.798 us; speedup 1.0000x reference)
//
#include <hip/hip_runtime.h>
#include <cstddef>

#define NN 100000
#define NE 640000

__device__ __forceinline__ int f2ord(float f) {
    int i = __float_as_int(f);
    return i >= 0 ? i : (i ^ 0x7fffffff);
}

// K1: node_score[n] = dot(node_features[n], mean_h attn_W[0:128])
__global__ __launch_bounds__(256) void k_node_score(
    const float* __restrict__ nf, const float* __restrict__ attn_W,
    float* __restrict__ node_score)
{
    const int lane = threadIdx.x & 63;
    const int wid  = blockIdx.x * 4 + (threadIdx.x >> 6);
    const int nw   = gridDim.x * 4;
    const float w0 = 0.25f * (attn_W[lane*4+0] + attn_W[lane*4+1] +
                              attn_W[lane*4+2] + attn_W[lane*4+3]);
    const float w1 = 0.25f * (attn_W[(lane+64)*4+0] + attn_W[(lane+64)*4+1] +
                              attn_W[(lane+64)*4+2] + attn_W[(lane+64)*4+3]);
    for (int n = wid; n < NN; n += nw) {
        const float* row = nf + (size_t)n * 128;
        float acc = fmaf(row[lane], w0, row[lane + 64] * w1);
        #pragma unroll
        for (int off = 32; off; off >>= 1) acc += __shfl_xor(acc, off);
        if (lane == 0) node_score[n] = acc;
    }
}

// K2: per-edge score = node_score[dst] + dot(ef, mean_h attn_W[128:192]) + bmean
//     store score, atomicMax into per-dst max (ordered-int trick)
__global__ __launch_bounds__(256) void k_edge_score(
    const float* __restrict__ ef, const float* __restrict__ attn_W,
    const float* __restrict__ attn_b, const int* __restrict__ dst_idx,
    const float* __restrict__ node_score,
    float* __restrict__ scores, int* __restrict__ maxI)
{
    const int lane = threadIdx.x & 63;
    const int wid  = blockIdx.x * 4 + (threadIdx.x >> 6);
    const int nw   = gridDim.x * 4;
    const int r = 128 + lane;
    const float wl = 0.25f * (attn_W[r*4+0] + attn_W[r*4+1] + attn_W[r*4+2] + attn_W[r*4+3]);
    const float bm = 0.25f * (attn_b[0] + attn_b[1] + attn_b[2] + attn_b[3]);
    for (int e = wid; e < NE; e += nw) {
        float acc = ef[(size_t)e * 64 + lane] * wl;
        #pragma unroll
        for (int off = 32; off; off >>= 1) acc += __shfl_xor(acc, off);
        if (lane == 0) {
            const int dd = dst_idx[e];
            const float s = acc + node_score[dd] + bm;
            scores[e] = s;
            atomicMax(&maxI[dd], f2ord(s));
        }
    }
}

// K3: exp_scores[e] = exp(score - max[dst]); atomicAdd sum_exp[dst]
__global__ __launch_bounds__(256) void k_exp_sum(
    const float* __restrict__ scores, const int* __restrict__ dst_idx,
    const int* __restrict__ maxI, float* __restrict__ expsc,
    float* __restrict__ sumexp)
{
    const int e = blockIdx.x * 256 + threadIdx.x;
    if (e >= NE) return;
    const int dd = dst_idx[e];
    const int mi = maxI[dd];
    const float m = __int_as_float(mi >= 0 ? mi : (mi ^ 0x7fffffff));
    const float es = expf(scores[e] - m);
    expsc[e] = es;
    atomicAdd(&sumexp[dd], es);
}

// K4: edge_values = ef @ ev_W + ev_b ; weighted atomic scatter into msg (=d_out)
//     block = 128 threads (thread d = output dim), 8 edges per iteration.
//     ev_W column for dim d lives in 64 VGPRs; edge rows staged in LDS
//     (reads are same-address broadcasts -> conflict-free).
__global__ __launch_bounds__(128) void k_edge_scatter(
    const float* __restrict__ ef, const float* __restrict__ evW,
    const float* __restrict__ evb, const int* __restrict__ dst_idx,
    const float* __restrict__ expsc, const float* __restrict__ sumexp,
    float* msg)
{
    __shared__ float efs[8][64];
    const int d = threadIdx.x;   // 0..127
    float wcol[64];
    #pragma unroll
    for (int k = 0; k < 64; ++k) wcol[k] = evW[k * 128 + d];
    const float bias = evb[d];
    const int nchunks = NE / 8;  // 80000; grid=2000 -> exactly 40 iters per block
    for (int c = blockIdx.x; c < nchunks; c += gridDim.x) {
        const int e0 = c * 8;
        const float* src = ef + (size_t)e0 * 64;
        #pragma unroll
        for (int i = 0; i < 4; ++i)
            (&efs[0][0])[i * 128 + d] = src[i * 128 + d];
        __syncthreads();
        float acc[8] = {0.f,0.f,0.f,0.f,0.f,0.f,0.f,0.f};
        #pragma unroll
        for (int k4 = 0; k4 < 64; k4 += 4) {
            #pragma unroll
            for (int j = 0; j < 8; ++j) {
                const float4 v = *reinterpret_cast<const float4*>(&efs[j][k4]);
                acc[j] = fmaf(v.x, wcol[k4+0], acc[j]);
                acc[j] = fmaf(v.y, wcol[k4+1], acc[j]);
                acc[j] = fmaf(v.z, wcol[k4+2], acc[j]);
                acc[j] = fmaf(v.w, wcol[k4+3], acc[j]);
            }
        }
        #pragma unroll
        for (int j = 0; j < 8; ++j) {
            const int e = e0 + j;
            const int dd = dst_idx[e];
            const float aw = expsc[e] / (sumexp[dd] + 1e-6f);
            atomicAdd(&msg[(size_t)dd * 128 + d], (acc[j] + bias) * aw);
        }
        __syncthreads();
    }
}

// K5: out = nf + relu(msg@W1 + b1)@W2 + b2, fused; 16 nodes per block of 128.
//     In-place on d_out (msg tile staged to LDS before any store).
__global__ __launch_bounds__(128) void k_node_update(
    const float* __restrict__ nf, const float* msg,
    const float* __restrict__ W1, const float* __restrict__ b1,
    const float* __restrict__ W2, const float* __restrict__ b2,
    float* out)
{
    __shared__ float ms[16][128];
    __shared__ float h1s[16][128];
    const int d  = threadIdx.x;       // 0..127
    const int n0 = blockIdx.x * 16;   // grid = 6250 exact

    #pragma unroll
    for (int i = 0; i < 16; ++i)
        ms[i][d] = msg[(size_t)(n0 + i) * 128 + d];

    float wc[128];
    #pragma unroll
    for (int k = 0; k < 128; ++k) wc[k] = W1[k * 128 + d];
    const float bb1 = b1[d];
    __syncthreads();

    for (int j = 0; j < 16; ++j) {
        float a0 = bb1, a1 = 0.f, a2 = 0.f, a3 = 0.f;
        #pragma unroll
        for (int k4 = 0; k4 < 128; k4 += 16) {
            const float4 v0 = *reinterpret_cast<const float4*>(&ms[j][k4+0]);
            const float4 v1 = *reinterpret_cast<const float4*>(&ms[j][k4+4]);
            const float4 v2 = *reinterpret_cast<const float4*>(&ms[j][k4+8]);
            const float4 v3 = *reinterpret_cast<const float4*>(&ms[j][k4+12]);
            a0 = fmaf(v0.x, wc[k4+0], a0);  a0 = fmaf(v0.y, wc[k4+1], a0);
            a0 = fmaf(v0.z, wc[k4+2], a0);  a0 = fmaf(v0.w, wc[k4+3], a0);
            a1 = fmaf(v1.x, wc[k4+4], a1);  a1 = fmaf(v1.y, wc[k4+5], a1);
            a1 = fmaf(v1.z, wc[k4+6], a1);  a1 = fmaf(v1.w, wc[k4+7], a1);
            a2 = fmaf(v2.x, wc[k4+8], a2);  a2 = fmaf(v2.y, wc[k4+9], a2);
            a2 = fmaf(v2.z, wc[k4+10], a2); a2 = fmaf(v2.w, wc[k4+11], a2);
            a3 = fmaf(v3.x, wc[k4+12], a3); a3 = fmaf(v3.y, wc[k4+13], a3);
            a3 = fmaf(v3.z, wc[k4+14], a3); a3 = fmaf(v3.w, wc[k4+15], a3);
        }
        h1s[j][d] = fmaxf((a0 + a1) + (a2 + a3), 0.f);
    }

    #pragma unroll
    for (int k = 0; k < 128; ++k) wc[k] = W2[k * 128 + d];
    const float bb2 = b2[d];
    __syncthreads();

    for (int j = 0; j < 16; ++j) {
        float a0 = bb2, a1 = 0.f, a2 = 0.f, a3 = 0.f;
        #pragma unroll
        for (int k4 = 0; k4 < 128; k4 += 16) {
            const float4 v0 = *reinterpret_cast<const float4*>(&h1s[j][k4+0]);
            const float4 v1 = *reinterpret_cast<const float4*>(&h1s[j][k4+4]);
            const float4 v2 = *reinterpret_cast<const float4*>(&h1s[j][k4+8]);
            const float4 v3 = *reinterpret_cast<const float4*>(&h1s[j][k4+12]);
            a0 = fmaf(v0.x, wc[k4+0], a0);  a0 = fmaf(v0.y, wc[k4+1], a0);
            a0 = fmaf(v0.z, wc[k4+2], a0);  a0 = fmaf(v0.w, wc[k4+3], a0);
            a1 = fmaf(v1.x, wc[k4+4], a1);  a1 = fmaf(v1.y, wc[k4+5], a1);
            a1 = fmaf(v1.z, wc[k4+6], a1);  a1 = fmaf(v1.w, wc[k4+7], a1);
            a2 = fmaf(v2.x, wc[k4+8], a2);  a2 = fmaf(v2.y, wc[k4+9], a2);
            a2 = fmaf(v2.z, wc[k4+10], a2); a2 = fmaf(v2.w, wc[k4+11], a2);
            a3 = fmaf(v3.x, wc[k4+12], a3); a3 = fmaf(v3.y, wc[k4+13], a3);
            a3 = fmaf(v3.z, wc[k4+14], a3); a3 = fmaf(v3.w, wc[k4+15], a3);
        }
        const size_t idx = (size_t)(n0 + j) * 128 + d;
        out[idx] = nf[idx] + ((a0 + a1) + (a2 + a3));
    }
}

extern "C" void kernel_launch(void* const* d_in, const int* in_sizes, int n_in,
                              void* d_out, int out_size, void* d_ws, size_t ws_size,
                              hipStream_t stream)
{
    const float* nf     = (const float*)d_in[0];
    const float* ef     = (const float*)d_in[1];
    const float* attn_W = (const float*)d_in[2];
    const float* attn_b = (const float*)d_in[3];
    const float* evW    = (const float*)d_in[4];
    const float* evb    = (const float*)d_in[5];
    const float* W1     = (const float*)d_in[6];
    const float* b1     = (const float*)d_in[7];
    const float* W2     = (const float*)d_in[8];
    const float* b2     = (const float*)d_in[9];
    const int*   eidx   = (const int*)d_in[10];
    const int*   dst    = eidx + NE;          // edge_index row 1
    float* out = (float*)d_out;

    char* ws = (char*)d_ws;
    float* node_score = (float*)(ws + 0);         //  400,000 B
    int*   maxI       = (int*)  (ws + 409600);    //  400,000 B
    float* sumexp     = (float*)(ws + 819200);    //  400,000 B
    float* scores     = (float*)(ws + 1228800);   // 2,560,000 B
    float* expsc      = (float*)(ws + 3788800);   // 2,560,000 B  (total 6.35 MB)

    // init accumulators (ws/d_out are poisoned once, never re-poisoned)
    hipMemsetAsync(maxI, 0x80, NN * sizeof(int), stream);      // ordered-int ~ -3.4e38
    hipMemsetAsync(sumexp, 0, NN * sizeof(float), stream);
    hipMemsetAsync(d_out, 0, (size_t)NN * 128 * sizeof(float), stream);

    k_node_score  <<<512,  256, 0, stream>>>(nf, attn_W, node_score);
    k_edge_score  <<<2048, 256, 0, stream>>>(ef, attn_W, attn_b, dst, node_score, scores, maxI);
    k_exp_sum     <<<2500, 256, 0, stream>>>(scores, dst, maxI, expsc, sumexp);
    k_edge_scatter<<<2000, 128, 0, stream>>>(ef, evW, evb, dst, expsc, sumexp, out);
    k_node_update <<<6250, 128, 0, stream>>>(nf, out, W1, b1, W2, b2, out);
}

// Round 2
// 529.445 us; speedup vs baseline: 1.6296x; 1.6296x over previous
//
#include <hip/hip_runtime.h>
#include <cstddef>

#define NN 100000
#define NE 640000

typedef short short8 __attribute__((ext_vector_type(8)));
typedef float f32x4  __attribute__((ext_vector_type(4)));

__device__ __forceinline__ int f2ord(float f) {
    int i = __float_as_int(f);
    return i >= 0 ? i : (i ^ 0x7fffffff);
}

__device__ __forceinline__ short f2bf(float f) {   // RNE f32->bf16
    union { float f; unsigned u; } v; v.f = f;
    unsigned r = (v.u + 0x7fffu + ((v.u >> 16) & 1u)) >> 16;
    return (short)r;
}

// K0: convert W1,W2 (128x128 f32, [k][n]) to bf16 TRANSPOSED [n][k] in ws
__global__ __launch_bounds__(256) void k_wcvt(
    const float* __restrict__ W1, const float* __restrict__ W2,
    ushort* __restrict__ W1t, ushort* __restrict__ W2t)
{
    const int tid = blockIdx.x * 256 + threadIdx.x;   // 0..16383
    if (tid >= 16384) return;
    const int n = tid >> 7, k = tid & 127;
    W1t[tid] = (ushort)f2bf(W1[k * 128 + n]);
    W2t[tid] = (ushort)f2bf(W2[k * 128 + n]);
}

// K1: node_score[n] = dot(node_features[n], mean_h attn_W[0:128])
__global__ __launch_bounds__(256) void k_node_score(
    const float* __restrict__ nf, const float* __restrict__ attn_W,
    float* __restrict__ node_score)
{
    const int lane = threadIdx.x & 63;
    const int wid  = blockIdx.x * 4 + (threadIdx.x >> 6);
    const int nw   = gridDim.x * 4;
    const float w0 = 0.25f * (attn_W[lane*4+0] + attn_W[lane*4+1] +
                              attn_W[lane*4+2] + attn_W[lane*4+3]);
    const float w1 = 0.25f * (attn_W[(lane+64)*4+0] + attn_W[(lane+64)*4+1] +
                              attn_W[(lane+64)*4+2] + attn_W[(lane+64)*4+3]);
    for (int n = wid; n < NN; n += nw) {
        const float* row = nf + (size_t)n * 128;
        float acc = fmaf(row[lane], w0, row[lane + 64] * w1);
        #pragma unroll
        for (int off = 32; off; off >>= 1) acc += __shfl_xor(acc, off);
        if (lane == 0) node_score[n] = acc;
    }
}

// K2: per-edge score; atomicMax per dst (ordered-int)
__global__ __launch_bounds__(256) void k_edge_score(
    const float* __restrict__ ef, const float* __restrict__ attn_W,
    const float* __restrict__ attn_b, const int* __restrict__ dst_idx,
    const float* __restrict__ node_score,
    float* __restrict__ scores, int* __restrict__ maxI)
{
    const int lane = threadIdx.x & 63;
    const int wid  = blockIdx.x * 4 + (threadIdx.x >> 6);
    const int nw   = gridDim.x * 4;
    const int r = 128 + lane;
    const float wl = 0.25f * (attn_W[r*4+0] + attn_W[r*4+1] + attn_W[r*4+2] + attn_W[r*4+3]);
    const float bm = 0.25f * (attn_b[0] + attn_b[1] + attn_b[2] + attn_b[3]);
    for (int e = wid; e < NE; e += nw) {
        float acc = ef[(size_t)e * 64 + lane] * wl;
        #pragma unroll
        for (int off = 32; off; off >>= 1) acc += __shfl_xor(acc, off);
        if (lane == 0) {
            const int dd = dst_idx[e];
            const float s = acc + node_score[dd] + bm;
            scores[e] = s;
            atomicMax(&maxI[dd], f2ord(s));
        }
    }
}

// K3: scores[e] <- exp(scores[e] - max[dst]) IN PLACE; atomicAdd sum_exp[dst]
__global__ __launch_bounds__(256) void k_exp_sum(
    float* scores, const int* __restrict__ dst_idx,
    const int* __restrict__ maxI, float* __restrict__ sumexp)
{
    const int e = blockIdx.x * 256 + threadIdx.x;
    if (e >= NE) return;
    const int dd = dst_idx[e];
    const int mi = maxI[dd];
    const float m = __int_as_float(mi >= 0 ? mi : (mi ^ 0x7fffffff));
    const float es = expf(scores[e] - m);
    scores[e] = es;
    atomicAdd(&sumexp[dd], es);
}

// K4: edge_values = ef @ ev_W + ev_b ; weighted atomic scatter into msg (=d_out)
__global__ __launch_bounds__(128) void k_edge_scatter(
    const float* __restrict__ ef, const float* __restrict__ evW,
    const float* __restrict__ evb, const int* __restrict__ dst_idx,
    const float* __restrict__ expsc, const float* __restrict__ sumexp,
    float* msg)
{
    __shared__ float efs[8][64];
    const int d = threadIdx.x;   // 0..127
    float wcol[64];
    #pragma unroll
    for (int k = 0; k < 64; ++k) wcol[k] = evW[k * 128 + d];
    const float bias = evb[d];
    const int nchunks = NE / 8;
    for (int c = blockIdx.x; c < nchunks; c += gridDim.x) {
        const int e0 = c * 8;
        const float* src = ef + (size_t)e0 * 64;
        #pragma unroll
        for (int i = 0; i < 4; ++i)
            (&efs[0][0])[i * 128 + d] = src[i * 128 + d];
        __syncthreads();
        float acc[8] = {0.f,0.f,0.f,0.f,0.f,0.f,0.f,0.f};
        #pragma unroll
        for (int k4 = 0; k4 < 64; k4 += 4) {
            #pragma unroll
            for (int j = 0; j < 8; ++j) {
                const float4 v = *reinterpret_cast<const float4*>(&efs[j][k4]);
                acc[j] = fmaf(v.x, wcol[k4+0], acc[j]);
                acc[j] = fmaf(v.y, wcol[k4+1], acc[j]);
                acc[j] = fmaf(v.z, wcol[k4+2], acc[j]);
                acc[j] = fmaf(v.w, wcol[k4+3], acc[j]);
            }
        }
        #pragma unroll
        for (int j = 0; j < 8; ++j) {
            const int e = e0 + j;
            const int dd = dst_idx[e];
            const float aw = expsc[e] / (sumexp[dd] + 1e-6f);
            atomicAdd(&msg[(size_t)dd * 128 + d], (acc[j] + bias) * aw);
        }
        __syncthreads();
    }
}

// K5: out = nf + relu(msg@W1 + b1)@W2 + b2 via bf16 MFMA.
// 4 waves/block; each wave owns a 16-node tile (wave-private LDS slice,
// NO __syncthreads -> tail waves may early-return safely).
__global__ __launch_bounds__(256) void k_mlp(
    const float* msg, const float* __restrict__ nf,
    const ushort* __restrict__ W1t, const float* __restrict__ b1,
    const ushort* __restrict__ W2t, const float* __restrict__ b2,
    float* out)
{
    __shared__ ushort h1s[4][16][136];   // pad 128->136: no stride-256B bank conflict
    const int wid  = threadIdx.x >> 6;
    const int lane = threadIdx.x & 63;
    const int n0   = blockIdx.x * 64 + wid * 16;
    if (n0 >= NN) return;                // 100000 % 16 == 0: tiles all-in or all-out

    const int r = lane & 15;             // A-row / B-col / D-col
    const int g = lane >> 4;             // k-group

    // A fragments from msg tile: a[t][j] = msg[n0+r][t*32 + g*8 + j]
    short8 a[4];
    const float* mrow = msg + (size_t)(n0 + r) * 128 + g * 8;
    #pragma unroll
    for (int t = 0; t < 4; ++t) {
        const float4 u0 = *reinterpret_cast<const float4*>(mrow + t * 32);
        const float4 u1 = *reinterpret_cast<const float4*>(mrow + t * 32 + 4);
        short8 p;
        p[0]=f2bf(u0.x); p[1]=f2bf(u0.y); p[2]=f2bf(u0.z); p[3]=f2bf(u0.w);
        p[4]=f2bf(u1.x); p[5]=f2bf(u1.y); p[6]=f2bf(u1.z); p[7]=f2bf(u1.w);
        a[t] = p;
    }

    // GEMM1 + bias + relu -> bf16 into wave-private LDS
    #pragma unroll
    for (int nt = 0; nt < 8; ++nt) {
        f32x4 acc = {0.f, 0.f, 0.f, 0.f};
        #pragma unroll
        for (int t = 0; t < 4; ++t) {
            const short8 b = *reinterpret_cast<const short8*>(
                W1t + (size_t)(nt * 16 + r) * 128 + t * 32 + g * 8);
            acc = __builtin_amdgcn_mfma_f32_16x16x32_bf16(a[t], b, acc, 0, 0, 0);
        }
        const float bias = b1[nt * 16 + r];
        #pragma unroll
        for (int i = 0; i < 4; ++i) {
            const float h = fmaxf(acc[i] + bias, 0.f);   // D row = g*4+i, col = nt*16+r
            h1s[wid][g * 4 + i][nt * 16 + r] = (ushort)f2bf(h);
        }
    }

    asm volatile("s_waitcnt lgkmcnt(0)" ::: "memory");   // wave-local LDS RAW fence

    // A2 fragments from LDS h1 tile
    short8 a2[4];
    #pragma unroll
    for (int t = 0; t < 4; ++t)
        a2[t] = *reinterpret_cast<const short8*>(&h1s[wid][r][t * 32 + g * 8]);

    // GEMM2 + bias + residual store
    #pragma unroll
    for (int nt = 0; nt < 8; ++nt) {
        f32x4 acc = {0.f, 0.f, 0.f, 0.f};
        #pragma unroll
        for (int t = 0; t < 4; ++t) {
            const short8 b = *reinterpret_cast<const short8*>(
                W2t + (size_t)(nt * 16 + r) * 128 + t * 32 + g * 8);
            acc = __builtin_amdgcn_mfma_f32_16x16x32_bf16(a2[t], b, acc, 0, 0, 0);
        }
        const float bias = b2[nt * 16 + r];
        #pragma unroll
        for (int i = 0; i < 4; ++i) {
            const size_t idx = (size_t)(n0 + g * 4 + i) * 128 + nt * 16 + r;
            out[idx] = nf[idx] + acc[i] + bias;
        }
    }
}

extern "C" void kernel_launch(void* const* d_in, const int* in_sizes, int n_in,
                              void* d_out, int out_size, void* d_ws, size_t ws_size,
                              hipStream_t stream)
{
    const float* nf     = (const float*)d_in[0];
    const float* ef     = (const float*)d_in[1];
    const float* attn_W = (const float*)d_in[2];
    const float* attn_b = (const float*)d_in[3];
    const float* evW    = (const float*)d_in[4];
    const float* evb    = (const float*)d_in[5];
    const float* W1     = (const float*)d_in[6];
    const float* b1     = (const float*)d_in[7];
    const float* W2     = (const float*)d_in[8];
    const float* b2     = (const float*)d_in[9];
    const int*   eidx   = (const int*)d_in[10];
    const int*   dst    = eidx + NE;
    float* out = (float*)d_out;

    char* ws = (char*)d_ws;
    float*  node_score = (float*) (ws + 0);        //  400 KB
    int*    maxI       = (int*)   (ws + 409600);   //  400 KB
    float*  sumexp     = (float*) (ws + 819200);   //  400 KB
    float*  scores     = (float*) (ws + 1228800);  // 2.56 MB (reused as exp_scores)
    ushort* W1t        = (ushort*)(ws + 3788800);  //   32 KB
    ushort* W2t        = (ushort*)(ws + 3821568);  //   32 KB  (total 3.85 MB)

    hipMemsetAsync(maxI, 0x80, NN * sizeof(int), stream);
    hipMemsetAsync(sumexp, 0, NN * sizeof(float), stream);
    hipMemsetAsync(d_out, 0, (size_t)NN * 128 * sizeof(float), stream);

    k_wcvt        <<<64,   256, 0, stream>>>(W1, W2, W1t, W2t);
    k_node_score  <<<512,  256, 0, stream>>>(nf, attn_W, node_score);
    k_edge_score  <<<2048, 256, 0, stream>>>(ef, attn_W, attn_b, dst, node_score, scores, maxI);
    k_exp_sum     <<<2500, 256, 0, stream>>>(scores, dst, maxI, sumexp);
    k_edge_scatter<<<2000, 128, 0, stream>>>(ef, evW, evb, dst, scores, sumexp, out);
    k_mlp         <<<1563, 256, 0, stream>>>(out, nf, W1t, b1, W2t, b2, out);
}

// Round 3
// 311.619 us; speedup vs baseline: 2.7688x; 1.6990x over previous
//
#include <hip/hip_runtime.h>
#include <cstddef>

#define NN 100000
#define NE 640000
#define NB_SCAN 391   // ceil(NN/256)

typedef short  short8   __attribute__((ext_vector_type(8)));
typedef float  f32x4    __attribute__((ext_vector_type(4)));
typedef ushort ushort4v __attribute__((ext_vector_type(4)));

__device__ __forceinline__ short f2bf(float f) {   // RNE f32->bf16
    union { float f; unsigned u; } v; v.f = f;
    unsigned r = (v.u + 0x7fffu + ((v.u >> 16) & 1u)) >> 16;
    return (short)r;
}

// K0: bf16-transpose weights: W1,W2 (128x128 [k][n]) -> [n][k]; evW (64x128 [k][n]) -> [n][k]
__global__ __launch_bounds__(256) void k_wcvt(
    const float* __restrict__ W1, const float* __restrict__ W2,
    const float* __restrict__ evW,
    ushort* __restrict__ W1t, ushort* __restrict__ W2t, ushort* __restrict__ evWt)
{
    const int tid = blockIdx.x * 256 + threadIdx.x;   // 64 blocks -> 0..16383
    if (tid < 16384) {
        const int n = tid >> 7, k = tid & 127;
        W1t[tid] = (ushort)f2bf(W1[k * 128 + n]);
        W2t[tid] = (ushort)f2bf(W2[k * 128 + n]);
    }
    if (tid < 8192) {
        const int n = tid >> 6, k = tid & 63;
        evWt[tid] = (ushort)f2bf(evW[k * 128 + n]);
    }
}

// K1: node_score[n] = dot(nf[n], mean_h attn_W[0:128])
__global__ __launch_bounds__(256) void k_node_score(
    const float* __restrict__ nf, const float* __restrict__ attn_W,
    float* __restrict__ node_score)
{
    const int lane = threadIdx.x & 63;
    const int wid  = blockIdx.x * 4 + (threadIdx.x >> 6);
    const int nw   = gridDim.x * 4;
    const float w0 = 0.25f * (attn_W[lane*4+0] + attn_W[lane*4+1] +
                              attn_W[lane*4+2] + attn_W[lane*4+3]);
    const float w1 = 0.25f * (attn_W[(lane+64)*4+0] + attn_W[(lane+64)*4+1] +
                              attn_W[(lane+64)*4+2] + attn_W[(lane+64)*4+3]);
    for (int n = wid; n < NN; n += nw) {
        const float* row = nf + (size_t)n * 128;
        float acc = fmaf(row[lane], w0, row[lane + 64] * w1);
        #pragma unroll
        for (int off = 32; off; off >>= 1) acc += __shfl_xor(acc, off);
        if (lane == 0) node_score[n] = acc;
    }
}

// K2: scores[e] = node_score[dst] + dot(ef, mean_h attn_W[128:192]) + bmean
//     plus in-degree histogram (int atomics). No float atomics.
__global__ __launch_bounds__(256) void k_edge_score(
    const float* __restrict__ ef, const float* __restrict__ attn_W,
    const float* __restrict__ attn_b, const int* __restrict__ dst_idx,
    const float* __restrict__ node_score,
    float* __restrict__ scores, int* __restrict__ count)
{
    const int lane = threadIdx.x & 63;
    const int wid  = blockIdx.x * 4 + (threadIdx.x >> 6);
    const int nw   = gridDim.x * 4;
    const int r = 128 + lane;
    const float wl = 0.25f * (attn_W[r*4+0] + attn_W[r*4+1] + attn_W[r*4+2] + attn_W[r*4+3]);
    const float bm = 0.25f * (attn_b[0] + attn_b[1] + attn_b[2] + attn_b[3]);
    for (int e = wid; e < NE; e += nw) {
        float acc = ef[(size_t)e * 64 + lane] * wl;
        #pragma unroll
        for (int off = 32; off; off >>= 1) acc += __shfl_xor(acc, off);
        if (lane == 0) {
            const int dd = dst_idx[e];
            scores[e] = acc + node_score[dd] + bm;
            atomicAdd(&count[dd], 1);
        }
    }
}

// Scan step A: per-block sums of count
__global__ __launch_bounds__(256) void k_scan_bsum(
    const int* __restrict__ count, int* __restrict__ bsum)
{
    __shared__ int s[256];
    const int t = threadIdx.x, i = blockIdx.x * 256 + t;
    s[t] = (i < NN) ? count[i] : 0;
    __syncthreads();
    for (int off = 128; off; off >>= 1) { if (t < off) s[t] += s[t + off]; __syncthreads(); }
    if (t == 0) bsum[blockIdx.x] = s[0];
}

// Scan step B: serial exclusive scan of 391 block sums; rowptr[NN] = NE
__global__ void k_scan_serial(const int* __restrict__ bsum, int* __restrict__ boff,
                              int* __restrict__ rowptr)
{
    if (blockIdx.x == 0 && threadIdx.x == 0) {
        int run = 0;
        for (int b = 0; b < NB_SCAN; ++b) { boff[b] = run; run += bsum[b]; }
        rowptr[NN] = run;   // == NE
    }
}

// Scan step C: in-block exclusive scan + block offset -> rowptr
__global__ __launch_bounds__(256) void k_scan_final(
    const int* __restrict__ count, const int* __restrict__ boff,
    int* __restrict__ rowptr)
{
    __shared__ int s[256];
    const int t = threadIdx.x, i = blockIdx.x * 256 + t;
    const int v = (i < NN) ? count[i] : 0;
    s[t] = v;
    __syncthreads();
    for (int off = 1; off < 256; off <<= 1) {
        const int x = (t >= off) ? s[t - off] : 0;
        __syncthreads();
        s[t] += x;
        __syncthreads();
    }
    if (i < NN) rowptr[i] = boff[blockIdx.x] + s[t] - v;
}

// K3: build permutation grouping edges by dst (CSR)
__global__ __launch_bounds__(256) void k_permute(
    const int* __restrict__ dst_idx, const int* __restrict__ rowptr,
    int* cursor, int* __restrict__ perm)
{
    const int e = blockIdx.x * 256 + threadIdx.x;
    if (e >= NE) return;
    const int dd = dst_idx[e];
    perm[rowptr[dd] + atomicAdd(&cursor[dd], 1)] = e;
}

// K4: per-node segment softmax + weighted ef aggregation, zero atomics.
// 16-lane group per node: pass1 max over scores, pass2 exp + accumulate.
__global__ __launch_bounds__(256) void k_aggregate(
    const float* __restrict__ ef, const float* __restrict__ scores,
    const int* __restrict__ perm, const int* __restrict__ rowptr,
    ushort* __restrict__ agg, float* __restrict__ msum)
{
    const int t  = threadIdx.x;
    const int sl = t & 15;
    const int n  = blockIdx.x * 16 + (t >> 4);   // grid 6250 -> exact
    const int beg = rowptr[n], end = rowptr[n + 1];

    float m = -3.0e38f;
    for (int i = beg + sl; i < end; i += 16)
        m = fmaxf(m, scores[perm[i]]);
    #pragma unroll
    for (int off = 8; off; off >>= 1)
        m = fmaxf(m, __shfl_xor(m, off, 16));

    f32x4 acc = {0.f, 0.f, 0.f, 0.f};
    float se = 0.f;
    for (int i = beg; i < end; ++i) {
        const int e = perm[i];                    // broadcast across group
        const float es = expf(scores[e] - m);
        const float4 v = *reinterpret_cast<const float4*>(ef + (size_t)e * 64 + sl * 4);
        acc[0] = fmaf(es, v.x, acc[0]);
        acc[1] = fmaf(es, v.y, acc[1]);
        acc[2] = fmaf(es, v.z, acc[2]);
        acc[3] = fmaf(es, v.w, acc[3]);
        se += es;
    }
    ushort4v o;
    o[0] = (ushort)f2bf(acc[0]); o[1] = (ushort)f2bf(acc[1]);
    o[2] = (ushort)f2bf(acc[2]); o[3] = (ushort)f2bf(acc[3]);
    *reinterpret_cast<ushort4v*>(agg + (size_t)n * 64 + sl * 4) = o;
    if (sl == 0) msum[n] = se;
}

// K5: fused  msg = (agg@evW)/(se+eps) + se/(se+eps)*evb ;
//            out = nf + relu(msg@W1+b1)@W2 + b2     (3 chained bf16 MFMA GEMMs)
// 4 waves/block, wave-private 16-node tile + LDS slice, no __syncthreads.
__global__ __launch_bounds__(256) void k_mega(
    const ushort* __restrict__ agg, const float* __restrict__ msum,
    const ushort* __restrict__ evWt, const float* __restrict__ evb,
    const ushort* __restrict__ W1t, const float* __restrict__ b1,
    const ushort* __restrict__ W2t, const float* __restrict__ b2,
    const float* __restrict__ nf, float* __restrict__ out)
{
    __shared__ ushort tls[4][16][136];   // wave-private, padded
    const int wid  = threadIdx.x >> 6;
    const int lane = threadIdx.x & 63;
    const int n0   = blockIdx.x * 64 + wid * 16;
    if (n0 >= NN) return;                // NN % 16 == 0
    const int r = lane & 15;
    const int g = lane >> 4;

    // --- phase 0: ev GEMM (K=64) + normalize + evb -> msg (bf16, LDS) ---
    short8 aev0 = *reinterpret_cast<const short8*>(agg + (size_t)(n0 + r) * 64 + g * 8);
    short8 aev1 = *reinterpret_cast<const short8*>(agg + (size_t)(n0 + r) * 64 + 32 + g * 8);
    float cf[4], cb[4];
    #pragma unroll
    for (int i = 0; i < 4; ++i) {
        const float s = msum[n0 + g * 4 + i];
        const float c = 1.f / (s + 1e-6f);
        cf[i] = c; cb[i] = s * c;
    }
    #pragma unroll
    for (int nt = 0; nt < 8; ++nt) {
        f32x4 acc = {0.f, 0.f, 0.f, 0.f};
        const short8 b0 = *reinterpret_cast<const short8*>(evWt + (nt * 16 + r) * 64 + g * 8);
        const short8 bq = *reinterpret_cast<const short8*>(evWt + (nt * 16 + r) * 64 + 32 + g * 8);
        acc = __builtin_amdgcn_mfma_f32_16x16x32_bf16(aev0, b0, acc, 0, 0, 0);
        acc = __builtin_amdgcn_mfma_f32_16x16x32_bf16(aev1, bq, acc, 0, 0, 0);
        const float eb = evb[nt * 16 + r];
        #pragma unroll
        for (int i = 0; i < 4; ++i)
            tls[wid][g * 4 + i][nt * 16 + r] = (ushort)f2bf(acc[i] * cf[i] + cb[i] * eb);
    }
    asm volatile("s_waitcnt lgkmcnt(0)" ::: "memory");

    // --- phase 1: GEMM1 + relu -> h1 (bf16, LDS, overwrites msg) ---
    short8 a1[4];
    #pragma unroll
    for (int t = 0; t < 4; ++t)
        a1[t] = *reinterpret_cast<const short8*>(&tls[wid][r][t * 32 + g * 8]);
    asm volatile("s_waitcnt lgkmcnt(0)" ::: "memory");   // reads done before overwrite
    #pragma unroll
    for (int nt = 0; nt < 8; ++nt) {
        f32x4 acc = {0.f, 0.f, 0.f, 0.f};
        #pragma unroll
        for (int t = 0; t < 4; ++t) {
            const short8 b = *reinterpret_cast<const short8*>(
                W1t + (size_t)(nt * 16 + r) * 128 + t * 32 + g * 8);
            acc = __builtin_amdgcn_mfma_f32_16x16x32_bf16(a1[t], b, acc, 0, 0, 0);
        }
        const float bias = b1[nt * 16 + r];
        #pragma unroll
        for (int i = 0; i < 4; ++i)
            tls[wid][g * 4 + i][nt * 16 + r] = (ushort)f2bf(fmaxf(acc[i] + bias, 0.f));
    }
    asm volatile("s_waitcnt lgkmcnt(0)" ::: "memory");

    // --- phase 2: GEMM2 + bias + residual ---
    short8 a2[4];
    #pragma unroll
    for (int t = 0; t < 4; ++t)
        a2[t] = *reinterpret_cast<const short8*>(&tls[wid][r][t * 32 + g * 8]);
    #pragma unroll
    for (int nt = 0; nt < 8; ++nt) {
        f32x4 acc = {0.f, 0.f, 0.f, 0.f};
        #pragma unroll
        for (int t = 0; t < 4; ++t) {
            const short8 b = *reinterpret_cast<const short8*>(
                W2t + (size_t)(nt * 16 + r) * 128 + t * 32 + g * 8);
            acc = __builtin_amdgcn_mfma_f32_16x16x32_bf16(a2[t], b, acc, 0, 0, 0);
        }
        const float bias = b2[nt * 16 + r];
        #pragma unroll
        for (int i = 0; i < 4; ++i) {
            const size_t idx = (size_t)(n0 + g * 4 + i) * 128 + nt * 16 + r;
            out[idx] = nf[idx] + acc[i] + bias;
        }
    }
}

extern "C" void kernel_launch(void* const* d_in, const int* in_sizes, int n_in,
                              void* d_out, int out_size, void* d_ws, size_t ws_size,
                              hipStream_t stream)
{
    const float* nf     = (const float*)d_in[0];
    const float* ef     = (const float*)d_in[1];
    const float* attn_W = (const float*)d_in[2];
    const float* attn_b = (const float*)d_in[3];
    const float* evW    = (const float*)d_in[4];
    const float* evb    = (const float*)d_in[5];
    const float* W1     = (const float*)d_in[6];
    const float* b1     = (const float*)d_in[7];
    const float* W2     = (const float*)d_in[8];
    const float* b2     = (const float*)d_in[9];
    const int*   eidx   = (const int*)d_in[10];
    const int*   dst    = eidx + NE;
    float* out = (float*)d_out;

    char* ws = (char*)d_ws;
    float*  scores  = (float*) (ws + 0);         // 2,560,000
    int*    perm    = (int*)   (ws + 2560000);   // 2,560,000
    int*    rowptr  = (int*)   (ws + 5120000);   //   400,004 (pad to 5,520,128)
    int*    count   = (int*)   (ws + 5520128);   //   400,000
    int*    cursor  = (int*)   (ws + 5920128);   //   400,000
    float*  nsc     = (float*) (ws + 6320128);   //   400,000
    float*  msum    = (float*) (ws + 6720128);   //   400,000
    ushort* agg     = (ushort*)(ws + 7120128);   // 12,800,000
    ushort* W1t     = (ushort*)(ws + 19920128);  //    32,768
    ushort* W2t     = (ushort*)(ws + 19952896);  //    32,768
    ushort* evWt    = (ushort*)(ws + 19985664);  //    16,384
    int*    bsum    = (int*)   (ws + 20002048);  //     1,564
    int*    boff    = (int*)   (ws + 20003648);  //     1,564  (total ~20.0 MB)

    hipMemsetAsync(count,  0, NN * sizeof(int), stream);
    hipMemsetAsync(cursor, 0, NN * sizeof(int), stream);

    k_wcvt       <<<64,   256, 0, stream>>>(W1, W2, evW, W1t, W2t, evWt);
    k_node_score <<<512,  256, 0, stream>>>(nf, attn_W, nsc);
    k_edge_score <<<2048, 256, 0, stream>>>(ef, attn_W, attn_b, dst, nsc, scores, count);
    k_scan_bsum  <<<NB_SCAN, 256, 0, stream>>>(count, bsum);
    k_scan_serial<<<1,    64,  0, stream>>>(bsum, boff, rowptr);
    k_scan_final <<<NB_SCAN, 256, 0, stream>>>(count, boff, rowptr);
    k_permute    <<<2500, 256, 0, stream>>>(dst, rowptr, cursor, perm);
    k_aggregate  <<<6250, 256, 0, stream>>>(ef, scores, perm, rowptr, agg, msum);
    k_mega       <<<1563, 256, 0, stream>>>(agg, msum, evWt, evb, W1t, b1, W2t, b2, nf, out);
}

// Round 4
// 259.368 us; speedup vs baseline: 3.3265x; 1.2015x over previous
//
#include <hip/hip_runtime.h>
#include <cstddef>

#define NN 100000
#define NE 640000
#define NB_SCAN 391   // ceil(NN/256)

typedef short  short8   __attribute__((ext_vector_type(8)));
typedef float  f32x4    __attribute__((ext_vector_type(4)));
typedef ushort ushort4v __attribute__((ext_vector_type(4)));

__device__ __forceinline__ short f2bf(float f) {   // RNE f32->bf16
    union { float f; unsigned u; } v; v.f = f;
    unsigned r = (v.u + 0x7fffu + ((v.u >> 16) & 1u)) >> 16;
    return (short)r;
}

// K0 (fused pre-pass):
//  a) weight bf16-transpose (W1,W2: 128x128 [k][n] -> [n][k]; evW: 64x128 -> [n][k])
//  b) node_score[n] = dot(nf[n], mean_h attn_W[0:128])  -- 16 lanes/node, f4 loads
//  c) in-degree histogram (int atomics)
__global__ __launch_bounds__(256) void k_pre(
    const float* __restrict__ nf, const float* __restrict__ attn_W,
    const float* __restrict__ W1, const float* __restrict__ W2,
    const float* __restrict__ evW, const int* __restrict__ dst_idx,
    float* __restrict__ node_score, int* __restrict__ count,
    ushort* __restrict__ W1t, ushort* __restrict__ W2t, ushort* __restrict__ evWt)
{
    const int t   = threadIdx.x;
    const int gid = blockIdx.x * 256 + t;

    if (gid < 16384) {                       // blocks 0..63
        const int n = gid >> 7, k = gid & 127;
        W1t[gid] = (ushort)f2bf(W1[k * 128 + n]);
        W2t[gid] = (ushort)f2bf(W2[k * 128 + n]);
        if (gid < 8192) {
            const int n2 = gid >> 6, k2 = gid & 63;
            evWt[gid] = (ushort)f2bf(evW[k2 * 128 + n2]);
        }
    }

    // node score: 16 nodes per block (grid 6250 -> exact)
    const int sl = t & 15;
    const int n  = blockIdx.x * 16 + (t >> 4);
    {
        float w[8];
        #pragma unroll
        for (int j = 0; j < 8; ++j) {
            const float4 r = *reinterpret_cast<const float4*>(attn_W + (sl * 8 + j) * 4);
            w[j] = 0.25f * (r.x + r.y + r.z + r.w);
        }
        const float* row = nf + (size_t)n * 128 + sl * 8;
        const float4 a = *reinterpret_cast<const float4*>(row);
        const float4 b = *reinterpret_cast<const float4*>(row + 4);
        float acc = a.x*w[0] + a.y*w[1] + a.z*w[2] + a.w*w[3]
                  + b.x*w[4] + b.y*w[5] + b.z*w[6] + b.w*w[7];
        #pragma unroll
        for (int off = 8; off; off >>= 1) acc += __shfl_xor(acc, off, 16);
        if (sl == 0) node_score[n] = acc;
    }

    // histogram (grid-stride; 6250*256 = 1.6M threads >= NE)
    for (int e = gid; e < NE; e += gridDim.x * 256)
        atomicAdd(&count[dst_idx[e]], 1);
}

// Scan step A: per-block sums of count
__global__ __launch_bounds__(256) void k_scan_bsum(
    const int* __restrict__ count, int* __restrict__ bsum)
{
    __shared__ int s[256];
    const int t = threadIdx.x, i = blockIdx.x * 256 + t;
    s[t] = (i < NN) ? count[i] : 0;
    __syncthreads();
    for (int off = 128; off; off >>= 1) { if (t < off) s[t] += s[t + off]; __syncthreads(); }
    if (t == 0) bsum[blockIdx.x] = s[0];
}

// Scan step B: serial exclusive scan of block sums; rowptr[NN] = NE
__global__ void k_scan_serial(const int* __restrict__ bsum, int* __restrict__ boff,
                              int* __restrict__ rowptr)
{
    if (blockIdx.x == 0 && threadIdx.x == 0) {
        int run = 0;
        for (int b = 0; b < NB_SCAN; ++b) { boff[b] = run; run += bsum[b]; }
        rowptr[NN] = run;   // == NE
    }
}

// Scan step C: in-block exclusive scan + block offset -> rowptr
__global__ __launch_bounds__(256) void k_scan_final(
    const int* __restrict__ count, const int* __restrict__ boff,
    int* __restrict__ rowptr)
{
    __shared__ int s[256];
    const int t = threadIdx.x, i = blockIdx.x * 256 + t;
    const int v = (i < NN) ? count[i] : 0;
    s[t] = v;
    __syncthreads();
    for (int off = 1; off < 256; off <<= 1) {
        const int x = (t >= off) ? s[t - off] : 0;
        __syncthreads();
        s[t] += x;
        __syncthreads();
    }
    if (i < NN) rowptr[i] = boff[blockIdx.x] + s[t] - v;
}

// K3: build permutation grouping edges by dst (CSR)
__global__ __launch_bounds__(256) void k_permute(
    const int* __restrict__ dst_idx, const int* __restrict__ rowptr,
    int* cursor, int* __restrict__ perm)
{
    const int e = blockIdx.x * 256 + threadIdx.x;
    if (e >= NE) return;
    const int dd = dst_idx[e];
    perm[rowptr[dd] + atomicAdd(&cursor[dd], 1)] = e;
}

// K4: fused per-node segment softmax + weighted ef aggregation.
// Scores computed ON THE FLY from ef rows (read once cold in pass 1,
// L1/L2-hot re-read in pass 2). Zero float atomics, zero extra ef pass.
__global__ __launch_bounds__(256) void k_aggregate(
    const float* __restrict__ ef, const float* __restrict__ attn_W,
    const float* __restrict__ attn_b, const float* __restrict__ node_score,
    const int* __restrict__ perm, const int* __restrict__ rowptr,
    ushort* __restrict__ agg, float* __restrict__ msum)
{
    const int t  = threadIdx.x;
    const int sl = t & 15;
    const int n  = blockIdx.x * 16 + (t >> 4);   // grid 6250 -> exact
    const int beg = rowptr[n], end = rowptr[n + 1];

    float4 wl;   // mean_h attn_W rows 128+sl*4 .. +3
    {
        const float4 r0 = *reinterpret_cast<const float4*>(attn_W + (128 + sl * 4 + 0) * 4);
        const float4 r1 = *reinterpret_cast<const float4*>(attn_W + (128 + sl * 4 + 1) * 4);
        const float4 r2 = *reinterpret_cast<const float4*>(attn_W + (128 + sl * 4 + 2) * 4);
        const float4 r3 = *reinterpret_cast<const float4*>(attn_W + (128 + sl * 4 + 3) * 4);
        wl.x = 0.25f * (r0.x + r0.y + r0.z + r0.w);
        wl.y = 0.25f * (r1.x + r1.y + r1.z + r1.w);
        wl.z = 0.25f * (r2.x + r2.y + r2.z + r2.w);
        wl.w = 0.25f * (r3.x + r3.y + r3.z + r3.w);
    }
    const float base = node_score[n]
                     + 0.25f * (attn_b[0] + attn_b[1] + attn_b[2] + attn_b[3]);

    // pass 1: segment max (score computed identically to pass 2 -> es <= 1)
    float m = -3.0e38f;
    for (int i = beg; i < end; ++i) {
        const int e = perm[i];
        const float4 v = *reinterpret_cast<const float4*>(ef + (size_t)e * 64 + sl * 4);
        float s = v.x * wl.x + v.y * wl.y + v.z * wl.z + v.w * wl.w;
        #pragma unroll
        for (int off = 8; off; off >>= 1) s += __shfl_xor(s, off, 16);
        m = fmaxf(m, s + base);
    }

    // pass 2: exp + weighted accumulate (ef row re-read is cache-hot)
    f32x4 acc = {0.f, 0.f, 0.f, 0.f};
    float se = 0.f;
    for (int i = beg; i < end; ++i) {
        const int e = perm[i];
        const float4 v = *reinterpret_cast<const float4*>(ef + (size_t)e * 64 + sl * 4);
        float s = v.x * wl.x + v.y * wl.y + v.z * wl.z + v.w * wl.w;
        #pragma unroll
        for (int off = 8; off; off >>= 1) s += __shfl_xor(s, off, 16);
        const float es = expf(s + base - m);
        acc[0] = fmaf(es, v.x, acc[0]);
        acc[1] = fmaf(es, v.y, acc[1]);
        acc[2] = fmaf(es, v.z, acc[2]);
        acc[3] = fmaf(es, v.w, acc[3]);
        se += es;
    }

    ushort4v o;
    o[0] = (ushort)f2bf(acc[0]); o[1] = (ushort)f2bf(acc[1]);
    o[2] = (ushort)f2bf(acc[2]); o[3] = (ushort)f2bf(acc[3]);
    *reinterpret_cast<ushort4v*>(agg + (size_t)n * 64 + sl * 4) = o;
    if (sl == 0) msum[n] = se;
}

// K5: fused  msg = (agg@evW)/(se+eps) + se/(se+eps)*evb ;
//            out = nf + relu(msg@W1+b1)@W2 + b2     (3 chained bf16 MFMA GEMMs)
__global__ __launch_bounds__(256) void k_mega(
    const ushort* __restrict__ agg, const float* __restrict__ msum,
    const ushort* __restrict__ evWt, const float* __restrict__ evb,
    const ushort* __restrict__ W1t, const float* __restrict__ b1,
    const ushort* __restrict__ W2t, const float* __restrict__ b2,
    const float* __restrict__ nf, float* __restrict__ out)
{
    __shared__ ushort tls[4][16][136];
    const int wid  = threadIdx.x >> 6;
    const int lane = threadIdx.x & 63;
    const int n0   = blockIdx.x * 64 + wid * 16;
    if (n0 >= NN) return;
    const int r = lane & 15;
    const int g = lane >> 4;

    short8 aev0 = *reinterpret_cast<const short8*>(agg + (size_t)(n0 + r) * 64 + g * 8);
    short8 aev1 = *reinterpret_cast<const short8*>(agg + (size_t)(n0 + r) * 64 + 32 + g * 8);
    float cf[4], cb[4];
    #pragma unroll
    for (int i = 0; i < 4; ++i) {
        const float s = msum[n0 + g * 4 + i];
        const float c = 1.f / (s + 1e-6f);
        cf[i] = c; cb[i] = s * c;
    }
    #pragma unroll
    for (int nt = 0; nt < 8; ++nt) {
        f32x4 acc = {0.f, 0.f, 0.f, 0.f};
        const short8 b0 = *reinterpret_cast<const short8*>(evWt + (nt * 16 + r) * 64 + g * 8);
        const short8 bq = *reinterpret_cast<const short8*>(evWt + (nt * 16 + r) * 64 + 32 + g * 8);
        acc = __builtin_amdgcn_mfma_f32_16x16x32_bf16(aev0, b0, acc, 0, 0, 0);
        acc = __builtin_amdgcn_mfma_f32_16x16x32_bf16(aev1, bq, acc, 0, 0, 0);
        const float eb = evb[nt * 16 + r];
        #pragma unroll
        for (int i = 0; i < 4; ++i)
            tls[wid][g * 4 + i][nt * 16 + r] = (ushort)f2bf(acc[i] * cf[i] + cb[i] * eb);
    }
    asm volatile("s_waitcnt lgkmcnt(0)" ::: "memory");

    short8 a1[4];
    #pragma unroll
    for (int t = 0; t < 4; ++t)
        a1[t] = *reinterpret_cast<const short8*>(&tls[wid][r][t * 32 + g * 8]);
    asm volatile("s_waitcnt lgkmcnt(0)" ::: "memory");
    #pragma unroll
    for (int nt = 0; nt < 8; ++nt) {
        f32x4 acc = {0.f, 0.f, 0.f, 0.f};
        #pragma unroll
        for (int t = 0; t < 4; ++t) {
            const short8 b = *reinterpret_cast<const short8*>(
                W1t + (size_t)(nt * 16 + r) * 128 + t * 32 + g * 8);
            acc = __builtin_amdgcn_mfma_f32_16x16x32_bf16(a1[t], b, acc, 0, 0, 0);
        }
        const float bias = b1[nt * 16 + r];
        #pragma unroll
        for (int i = 0; i < 4; ++i)
            tls[wid][g * 4 + i][nt * 16 + r] = (ushort)f2bf(fmaxf(acc[i] + bias, 0.f));
    }
    asm volatile("s_waitcnt lgkmcnt(0)" ::: "memory");

    short8 a2[4];
    #pragma unroll
    for (int t = 0; t < 4; ++t)
        a2[t] = *reinterpret_cast<const short8*>(&tls[wid][r][t * 32 + g * 8]);
    #pragma unroll
    for (int nt = 0; nt < 8; ++nt) {
        f32x4 acc = {0.f, 0.f, 0.f, 0.f};
        #pragma unroll
        for (int t = 0; t < 4; ++t) {
            const short8 b = *reinterpret_cast<const short8*>(
                W2t + (size_t)(nt * 16 + r) * 128 + t * 32 + g * 8);
            acc = __builtin_amdgcn_mfma_f32_16x16x32_bf16(a2[t], b, acc, 0, 0, 0);
        }
        const float bias = b2[nt * 16 + r];
        #pragma unroll
        for (int i = 0; i < 4; ++i) {
            const size_t idx = (size_t)(n0 + g * 4 + i) * 128 + nt * 16 + r;
            out[idx] = nf[idx] + acc[i] + bias;
        }
    }
}

extern "C" void kernel_launch(void* const* d_in, const int* in_sizes, int n_in,
                              void* d_out, int out_size, void* d_ws, size_t ws_size,
                              hipStream_t stream)
{
    const float* nf     = (const float*)d_in[0];
    const float* ef     = (const float*)d_in[1];
    const float* attn_W = (const float*)d_in[2];
    const float* attn_b = (const float*)d_in[3];
    const float* evW    = (const float*)d_in[4];
    const float* evb    = (const float*)d_in[5];
    const float* W1     = (const float*)d_in[6];
    const float* b1     = (const float*)d_in[7];
    const float* W2     = (const float*)d_in[8];
    const float* b2     = (const float*)d_in[9];
    const int*   eidx   = (const int*)d_in[10];
    const int*   dst    = eidx + NE;
    float* out = (float*)d_out;

    char* ws = (char*)d_ws;
    int*    perm    = (int*)   (ws + 0);         // 2,560,000
    int*    rowptr  = (int*)   (ws + 2560000);   //   400,004 (pad to 2,960,128)
    int*    count   = (int*)   (ws + 2960128);   //   400,000  } contiguous for
    int*    cursor  = (int*)   (ws + 3360128);   //   400,000  } single memset
    float*  nsc     = (float*) (ws + 3760128);   //   400,000
    float*  msum    = (float*) (ws + 4160128);   //   400,000
    ushort* agg     = (ushort*)(ws + 4560128);   // 12,800,000
    ushort* W1t     = (ushort*)(ws + 17360128);  //    32,768
    ushort* W2t     = (ushort*)(ws + 17392896);  //    32,768
    ushort* evWt    = (ushort*)(ws + 17425664);  //    16,384
    int*    bsum    = (int*)   (ws + 17442048);  //     1,564
    int*    boff    = (int*)   (ws + 17443648);  //     1,564  (total ~17.4 MB)

    hipMemsetAsync(count, 0, 2 * NN * sizeof(int), stream);   // count + cursor

    k_pre        <<<6250, 256, 0, stream>>>(nf, attn_W, W1, W2, evW, dst,
                                            nsc, count, W1t, W2t, evWt);
    k_scan_bsum  <<<NB_SCAN, 256, 0, stream>>>(count, bsum);
    k_scan_serial<<<1,    64,  0, stream>>>(bsum, boff, rowptr);
    k_scan_final <<<NB_SCAN, 256, 0, stream>>>(count, boff, rowptr);
    k_permute    <<<2500, 256, 0, stream>>>(dst, rowptr, cursor, perm);
    k_aggregate  <<<6250, 256, 0, stream>>>(ef, attn_W, attn_b, nsc, perm, rowptr, agg, msum);
    k_mega       <<<1563, 256, 0, stream>>>(agg, msum, evWt, evb, W1t, b1, W2t, b2, nf, out);
}

// Round 5
// 248.366 us; speedup vs baseline: 3.4739x; 1.0443x over previous
//
#include <hip/hip_runtime.h>
#include <cstddef>

#define NN 100000
#define NE 640000
#define NB_SCAN 391   // ceil(NN/256)

typedef short  short8   __attribute__((ext_vector_type(8)));
typedef float  f32x4    __attribute__((ext_vector_type(4)));
typedef ushort ushort4v __attribute__((ext_vector_type(4)));

__device__ __forceinline__ short f2bf(float f) {   // RNE f32->bf16
    union { float f; unsigned u; } v; v.f = f;
    unsigned r = (v.u + 0x7fffu + ((v.u >> 16) & 1u)) >> 16;
    return (short)r;
}
__device__ __forceinline__ float bf2f(ushort u) {
    union { unsigned u; float f; } v; v.u = ((unsigned)u) << 16;
    return v.f;
}

// K0 (fused pre-pass): weight bf16-transpose + node_score + in-degree histogram
__global__ __launch_bounds__(256) void k_pre(
    const float* __restrict__ nf, const float* __restrict__ attn_W,
    const float* __restrict__ W1, const float* __restrict__ W2,
    const float* __restrict__ evW, const int* __restrict__ dst_idx,
    float* __restrict__ node_score, int* __restrict__ count,
    ushort* __restrict__ W1t, ushort* __restrict__ W2t, ushort* __restrict__ evWt)
{
    const int t   = threadIdx.x;
    const int gid = blockIdx.x * 256 + t;

    if (gid < 16384) {
        const int n = gid >> 7, k = gid & 127;
        W1t[gid] = (ushort)f2bf(W1[k * 128 + n]);
        W2t[gid] = (ushort)f2bf(W2[k * 128 + n]);
        if (gid < 8192) {
            const int n2 = gid >> 6, k2 = gid & 63;
            evWt[gid] = (ushort)f2bf(evW[k2 * 128 + n2]);
        }
    }

    const int sl = t & 15;
    const int n  = blockIdx.x * 16 + (t >> 4);   // grid 6250 -> exact
    {
        float w[8];
        #pragma unroll
        for (int j = 0; j < 8; ++j) {
            const float4 r = *reinterpret_cast<const float4*>(attn_W + (sl * 8 + j) * 4);
            w[j] = 0.25f * (r.x + r.y + r.z + r.w);
        }
        const float* row = nf + (size_t)n * 128 + sl * 8;
        const float4 a = *reinterpret_cast<const float4*>(row);
        const float4 b = *reinterpret_cast<const float4*>(row + 4);
        float acc = a.x*w[0] + a.y*w[1] + a.z*w[2] + a.w*w[3]
                  + b.x*w[4] + b.y*w[5] + b.z*w[6] + b.w*w[7];
        #pragma unroll
        for (int off = 8; off; off >>= 1) acc += __shfl_xor(acc, off, 16);
        if (sl == 0) node_score[n] = acc;
    }

    for (int e = gid; e < NE; e += gridDim.x * 256)
        atomicAdd(&count[dst_idx[e]], 1);
}

// Scan A: per-block sums
__global__ __launch_bounds__(256) void k_scan_bsum(
    const int* __restrict__ count, int* __restrict__ bsum)
{
    __shared__ int s[256];
    const int t = threadIdx.x, i = blockIdx.x * 256 + t;
    s[t] = (i < NN) ? count[i] : 0;
    __syncthreads();
    for (int off = 128; off; off >>= 1) { if (t < off) s[t] += s[t + off]; __syncthreads(); }
    if (t == 0) bsum[blockIdx.x] = s[0];
}

// Scan B: serial scan of block sums
__global__ void k_scan_serial(const int* __restrict__ bsum, int* __restrict__ boff,
                              int* __restrict__ rowptr)
{
    if (blockIdx.x == 0 && threadIdx.x == 0) {
        int run = 0;
        for (int b = 0; b < NB_SCAN; ++b) { boff[b] = run; run += bsum[b]; }
        rowptr[NN] = run;   // == NE
    }
}

// Scan C: in-block exclusive scan
__global__ __launch_bounds__(256) void k_scan_final(
    const int* __restrict__ count, const int* __restrict__ boff,
    int* __restrict__ rowptr)
{
    __shared__ int s[256];
    const int t = threadIdx.x, i = blockIdx.x * 256 + t;
    const int v = (i < NN) ? count[i] : 0;
    s[t] = v;
    __syncthreads();
    for (int off = 1; off < 256; off <<= 1) {
        const int x = (t >= off) ? s[t - off] : 0;
        __syncthreads();
        s[t] += x;
        __syncthreads();
    }
    if (i < NN) rowptr[i] = boff[blockIdx.x] + s[t] - v;
}

// ---- FAST PATH ----
// K3f: streaming over edges: score + scatter {score, bf16 row} to CSR slot.
__global__ __launch_bounds__(256) void k_scatter(
    const float* __restrict__ ef, const float* __restrict__ attn_W,
    const float* __restrict__ attn_b, const int* __restrict__ dst_idx,
    const float* __restrict__ node_score, const int* __restrict__ rowptr,
    int* cursor, float* __restrict__ s_srt, ushort* __restrict__ ef_srt)
{
    const int t  = threadIdx.x;
    const int sl = t & 15;
    const int g0 = blockIdx.x * 16 + (t >> 4);
    const int gs = gridDim.x * 16;

    float4 wl;
    {
        const float4 r0 = *reinterpret_cast<const float4*>(attn_W + (128 + sl * 4 + 0) * 4);
        const float4 r1 = *reinterpret_cast<const float4*>(attn_W + (128 + sl * 4 + 1) * 4);
        const float4 r2 = *reinterpret_cast<const float4*>(attn_W + (128 + sl * 4 + 2) * 4);
        const float4 r3 = *reinterpret_cast<const float4*>(attn_W + (128 + sl * 4 + 3) * 4);
        wl.x = 0.25f * (r0.x + r0.y + r0.z + r0.w);
        wl.y = 0.25f * (r1.x + r1.y + r1.z + r1.w);
        wl.z = 0.25f * (r2.x + r2.y + r2.z + r2.w);
        wl.w = 0.25f * (r3.x + r3.y + r3.z + r3.w);
    }
    const float bm = 0.25f * (attn_b[0] + attn_b[1] + attn_b[2] + attn_b[3]);

    for (int e = g0; e < NE; e += gs) {
        const float4 v = *reinterpret_cast<const float4*>(ef + (size_t)e * 64 + sl * 4);
        float s = v.x * wl.x + v.y * wl.y + v.z * wl.z + v.w * wl.w;
        #pragma unroll
        for (int off = 8; off; off >>= 1) s += __shfl_xor(s, off, 16);
        int pos;
        if (sl == 0) {
            const int dd = dst_idx[e];
            pos = rowptr[dd] + atomicAdd(&cursor[dd], 1);
            s_srt[pos] = s + node_score[dd] + bm;
        }
        pos = __shfl(pos, 0, 16);
        ushort4v o;
        o[0] = (ushort)f2bf(v.x); o[1] = (ushort)f2bf(v.y);
        o[2] = (ushort)f2bf(v.z); o[3] = (ushort)f2bf(v.w);
        *reinterpret_cast<ushort4v*>(ef_srt + (size_t)pos * 64 + sl * 4) = o;
    }
}

// K4f: per-node softmax+aggregate over CONTIGUOUS sorted segments.
__global__ __launch_bounds__(256) void k_agg_stream(
    const float* __restrict__ s_srt, const ushort* __restrict__ ef_srt,
    const int* __restrict__ rowptr, ushort* __restrict__ agg,
    float* __restrict__ msum)
{
    const int t  = threadIdx.x;
    const int sl = t & 15;
    const int n  = blockIdx.x * 16 + (t >> 4);   // grid 6250 -> exact
    const int beg = rowptr[n], end = rowptr[n + 1];

    float m = -3.0e38f;
    for (int i = beg + sl; i < end; i += 16)
        m = fmaxf(m, s_srt[i]);
    #pragma unroll
    for (int off = 8; off; off >>= 1)
        m = fmaxf(m, __shfl_xor(m, off, 16));

    f32x4 acc = {0.f, 0.f, 0.f, 0.f};
    float se = 0.f;
    int i = beg;
    for (; i + 2 <= end; i += 2) {           // unroll 2 for load ILP
        const float s0 = s_srt[i], s1 = s_srt[i + 1];
        const ushort4v r0 = *reinterpret_cast<const ushort4v*>(ef_srt + (size_t)i * 64 + sl * 4);
        const ushort4v r1 = *reinterpret_cast<const ushort4v*>(ef_srt + (size_t)(i + 1) * 64 + sl * 4);
        const float e0 = expf(s0 - m), e1 = expf(s1 - m);
        acc[0] = fmaf(e0, bf2f(r0[0]), acc[0]); acc[1] = fmaf(e0, bf2f(r0[1]), acc[1]);
        acc[2] = fmaf(e0, bf2f(r0[2]), acc[2]); acc[3] = fmaf(e0, bf2f(r0[3]), acc[3]);
        acc[0] = fmaf(e1, bf2f(r1[0]), acc[0]); acc[1] = fmaf(e1, bf2f(r1[1]), acc[1]);
        acc[2] = fmaf(e1, bf2f(r1[2]), acc[2]); acc[3] = fmaf(e1, bf2f(r1[3]), acc[3]);
        se += e0 + e1;
    }
    for (; i < end; ++i) {
        const float s0 = s_srt[i];
        const ushort4v r0 = *reinterpret_cast<const ushort4v*>(ef_srt + (size_t)i * 64 + sl * 4);
        const float e0 = expf(s0 - m);
        acc[0] = fmaf(e0, bf2f(r0[0]), acc[0]); acc[1] = fmaf(e0, bf2f(r0[1]), acc[1]);
        acc[2] = fmaf(e0, bf2f(r0[2]), acc[2]); acc[3] = fmaf(e0, bf2f(r0[3]), acc[3]);
        se += e0;
    }

    ushort4v o;
    o[0] = (ushort)f2bf(acc[0]); o[1] = (ushort)f2bf(acc[1]);
    o[2] = (ushort)f2bf(acc[2]); o[3] = (ushort)f2bf(acc[3]);
    *reinterpret_cast<ushort4v*>(agg + (size_t)n * 64 + sl * 4) = o;
    if (sl == 0) msum[n] = se;
}

// ---- FALLBACK PATH (R4, proven) ----
__global__ __launch_bounds__(256) void k_permute(
    const int* __restrict__ dst_idx, const int* __restrict__ rowptr,
    int* cursor, int* __restrict__ perm)
{
    const int e = blockIdx.x * 256 + threadIdx.x;
    if (e >= NE) return;
    const int dd = dst_idx[e];
    perm[rowptr[dd] + atomicAdd(&cursor[dd], 1)] = e;
}

__global__ __launch_bounds__(256) void k_aggregate(
    const float* __restrict__ ef, const float* __restrict__ attn_W,
    const float* __restrict__ attn_b, const float* __restrict__ node_score,
    const int* __restrict__ perm, const int* __restrict__ rowptr,
    ushort* __restrict__ agg, float* __restrict__ msum)
{
    const int t  = threadIdx.x;
    const int sl = t & 15;
    const int n  = blockIdx.x * 16 + (t >> 4);
    const int beg = rowptr[n], end = rowptr[n + 1];

    float4 wl;
    {
        const float4 r0 = *reinterpret_cast<const float4*>(attn_W + (128 + sl * 4 + 0) * 4);
        const float4 r1 = *reinterpret_cast<const float4*>(attn_W + (128 + sl * 4 + 1) * 4);
        const float4 r2 = *reinterpret_cast<const float4*>(attn_W + (128 + sl * 4 + 2) * 4);
        const float4 r3 = *reinterpret_cast<const float4*>(attn_W + (128 + sl * 4 + 3) * 4);
        wl.x = 0.25f * (r0.x + r0.y + r0.z + r0.w);
        wl.y = 0.25f * (r1.x + r1.y + r1.z + r1.w);
        wl.z = 0.25f * (r2.x + r2.y + r2.z + r2.w);
        wl.w = 0.25f * (r3.x + r3.y + r3.z + r3.w);
    }
    const float base = node_score[n]
                     + 0.25f * (attn_b[0] + attn_b[1] + attn_b[2] + attn_b[3]);

    float m = -3.0e38f;
    for (int i = beg; i < end; ++i) {
        const int e = perm[i];
        const float4 v = *reinterpret_cast<const float4*>(ef + (size_t)e * 64 + sl * 4);
        float s = v.x * wl.x + v.y * wl.y + v.z * wl.z + v.w * wl.w;
        #pragma unroll
        for (int off = 8; off; off >>= 1) s += __shfl_xor(s, off, 16);
        m = fmaxf(m, s + base);
    }

    f32x4 acc = {0.f, 0.f, 0.f, 0.f};
    float se = 0.f;
    for (int i = beg; i < end; ++i) {
        const int e = perm[i];
        const float4 v = *reinterpret_cast<const float4*>(ef + (size_t)e * 64 + sl * 4);
        float s = v.x * wl.x + v.y * wl.y + v.z * wl.z + v.w * wl.w;
        #pragma unroll
        for (int off = 8; off; off >>= 1) s += __shfl_xor(s, off, 16);
        const float es = expf(s + base - m);
        acc[0] = fmaf(es, v.x, acc[0]);
        acc[1] = fmaf(es, v.y, acc[1]);
        acc[2] = fmaf(es, v.z, acc[2]);
        acc[3] = fmaf(es, v.w, acc[3]);
        se += es;
    }

    ushort4v o;
    o[0] = (ushort)f2bf(acc[0]); o[1] = (ushort)f2bf(acc[1]);
    o[2] = (ushort)f2bf(acc[2]); o[3] = (ushort)f2bf(acc[3]);
    *reinterpret_cast<ushort4v*>(agg + (size_t)n * 64 + sl * 4) = o;
    if (sl == 0) msum[n] = se;
}

// K5: msg = (agg@evW)/(se+eps) + se/(se+eps)*evb ; out = nf + relu(msg@W1+b1)@W2 + b2
__global__ __launch_bounds__(256) void k_mega(
    const ushort* __restrict__ agg, const float* __restrict__ msum,
    const ushort* __restrict__ evWt, const float* __restrict__ evb,
    const ushort* __restrict__ W1t, const float* __restrict__ b1,
    const ushort* __restrict__ W2t, const float* __restrict__ b2,
    const float* __restrict__ nf, float* __restrict__ out)
{
    __shared__ ushort tls[4][16][136];
    const int wid  = threadIdx.x >> 6;
    const int lane = threadIdx.x & 63;
    const int n0   = blockIdx.x * 64 + wid * 16;
    if (n0 >= NN) return;
    const int r = lane & 15;
    const int g = lane >> 4;

    short8 aev0 = *reinterpret_cast<const short8*>(agg + (size_t)(n0 + r) * 64 + g * 8);
    short8 aev1 = *reinterpret_cast<const short8*>(agg + (size_t)(n0 + r) * 64 + 32 + g * 8);
    float cf[4], cb[4];
    #pragma unroll
    for (int i = 0; i < 4; ++i) {
        const float s = msum[n0 + g * 4 + i];
        const float c = 1.f / (s + 1e-6f);
        cf[i] = c; cb[i] = s * c;
    }
    #pragma unroll
    for (int nt = 0; nt < 8; ++nt) {
        f32x4 acc = {0.f, 0.f, 0.f, 0.f};
        const short8 b0 = *reinterpret_cast<const short8*>(evWt + (nt * 16 + r) * 64 + g * 8);
        const short8 bq = *reinterpret_cast<const short8*>(evWt + (nt * 16 + r) * 64 + 32 + g * 8);
        acc = __builtin_amdgcn_mfma_f32_16x16x32_bf16(aev0, b0, acc, 0, 0, 0);
        acc = __builtin_amdgcn_mfma_f32_16x16x32_bf16(aev1, bq, acc, 0, 0, 0);
        const float eb = evb[nt * 16 + r];
        #pragma unroll
        for (int i = 0; i < 4; ++i)
            tls[wid][g * 4 + i][nt * 16 + r] = (ushort)f2bf(acc[i] * cf[i] + cb[i] * eb);
    }
    asm volatile("s_waitcnt lgkmcnt(0)" ::: "memory");

    short8 a1[4];
    #pragma unroll
    for (int t = 0; t < 4; ++t)
        a1[t] = *reinterpret_cast<const short8*>(&tls[wid][r][t * 32 + g * 8]);
    asm volatile("s_waitcnt lgkmcnt(0)" ::: "memory");
    #pragma unroll
    for (int nt = 0; nt < 8; ++nt) {
        f32x4 acc = {0.f, 0.f, 0.f, 0.f};
        #pragma unroll
        for (int t = 0; t < 4; ++t) {
            const short8 b = *reinterpret_cast<const short8*>(
                W1t + (size_t)(nt * 16 + r) * 128 + t * 32 + g * 8);
            acc = __builtin_amdgcn_mfma_f32_16x16x32_bf16(a1[t], b, acc, 0, 0, 0);
        }
        const float bias = b1[nt * 16 + r];
        #pragma unroll
        for (int i = 0; i < 4; ++i)
            tls[wid][g * 4 + i][nt * 16 + r] = (ushort)f2bf(fmaxf(acc[i] + bias, 0.f));
    }
    asm volatile("s_waitcnt lgkmcnt(0)" ::: "memory");

    short8 a2[4];
    #pragma unroll
    for (int t = 0; t < 4; ++t)
        a2[t] = *reinterpret_cast<const short8*>(&tls[wid][r][t * 32 + g * 8]);
    #pragma unroll
    for (int nt = 0; nt < 8; ++nt) {
        f32x4 acc = {0.f, 0.f, 0.f, 0.f};
        #pragma unroll
        for (int t = 0; t < 4; ++t) {
            const short8 b = *reinterpret_cast<const short8*>(
                W2t + (size_t)(nt * 16 + r) * 128 + t * 32 + g * 8);
            acc = __builtin_amdgcn_mfma_f32_16x16x32_bf16(a2[t], b, acc, 0, 0, 0);
        }
        const float bias = b2[nt * 16 + r];
        #pragma unroll
        for (int i = 0; i < 4; ++i) {
            const size_t idx = (size_t)(n0 + g * 4 + i) * 128 + nt * 16 + r;
            out[idx] = nf[idx] + acc[i] + bias;
        }
    }
}

extern "C" void kernel_launch(void* const* d_in, const int* in_sizes, int n_in,
                              void* d_out, int out_size, void* d_ws, size_t ws_size,
                              hipStream_t stream)
{
    const float* nf     = (const float*)d_in[0];
    const float* ef     = (const float*)d_in[1];
    const float* attn_W = (const float*)d_in[2];
    const float* attn_b = (const float*)d_in[3];
    const float* evW    = (const float*)d_in[4];
    const float* evb    = (const float*)d_in[5];
    const float* W1     = (const float*)d_in[6];
    const float* b1     = (const float*)d_in[7];
    const float* W2     = (const float*)d_in[8];
    const float* b2     = (const float*)d_in[9];
    const int*   eidx   = (const int*)d_in[10];
    const int*   dst    = eidx + NE;
    float* out = (float*)d_out;

    char* ws = (char*)d_ws;
    int*    count  = (int*)   (ws + 0);          //   400,000
    int*    cursor = (int*)   (ws + 400000);     //   400,000
    int*    rowptr = (int*)   (ws + 800000);     //   400,004 (pad -> 1,200,128)
    float*  nsc    = (float*) (ws + 1200128);    //   400,000
    float*  msum   = (float*) (ws + 1600128);    //   400,000
    float*  s_srt  = (float*) (ws + 2000128);    // 2,560,000
    ushort* agg    = (ushort*)(ws + 4560128);    // 12,800,000
    ushort* W1t    = (ushort*)(ws + 17360128);   //    32,768
    ushort* W2t    = (ushort*)(ws + 17392896);   //    32,768
    ushort* evWt   = (ushort*)(ws + 17425664);   //    16,384
    int*    bsum   = (int*)   (ws + 17442048);   //     1,664
    int*    boff   = (int*)   (ws + 17443712);   //     1,664
    char*   tail   =           ws + 17445376;    // fast: ef_srt 81,920,000 | fb: perm 2,560,000
    const bool fast = ws_size >= (size_t)17445376 + 81920000;

    hipMemsetAsync(count, 0, 800000, stream);    // count + cursor

    k_pre        <<<6250, 256, 0, stream>>>(nf, attn_W, W1, W2, evW, dst,
                                            nsc, count, W1t, W2t, evWt);
    k_scan_bsum  <<<NB_SCAN, 256, 0, stream>>>(count, bsum);
    k_scan_serial<<<1,    64,  0, stream>>>(bsum, boff, rowptr);
    k_scan_final <<<NB_SCAN, 256, 0, stream>>>(count, boff, rowptr);

    if (fast) {
        ushort* ef_srt = (ushort*)tail;
        k_scatter   <<<5000, 256, 0, stream>>>(ef, attn_W, attn_b, dst, nsc,
                                               rowptr, cursor, s_srt, ef_srt);
        k_agg_stream<<<6250, 256, 0, stream>>>(s_srt, ef_srt, rowptr, agg, msum);
    } else {
        int* perm = (int*)tail;
        k_permute   <<<2500, 256, 0, stream>>>(dst, rowptr, cursor, perm);
        k_aggregate <<<6250, 256, 0, stream>>>(ef, attn_W, attn_b, nsc, perm,
                                               rowptr, agg, msum);
    }
    k_mega       <<<1563, 256, 0, stream>>>(agg, msum, evWt, evb, W1t, b1, W2t, b2, nf, out);
}

// Round 6
// 225.615 us; speedup vs baseline: 3.8242x; 1.1008x over previous
//
#include <hip/hip_runtime.h>
#include <cstddef>

#define NN 100000
#define NE 640000
#define NB_SCAN 391   // ceil(NN/256)

typedef short  short8   __attribute__((ext_vector_type(8)));
typedef float  f32x4    __attribute__((ext_vector_type(4)));
typedef ushort ushort4v __attribute__((ext_vector_type(4)));

__device__ __forceinline__ short f2bf(float f) {   // RNE f32->bf16
    union { float f; unsigned u; } v; v.f = f;
    unsigned r = (v.u + 0x7fffu + ((v.u >> 16) & 1u)) >> 16;
    return (short)r;
}
__device__ __forceinline__ float bf2f(ushort u) {
    union { unsigned u; float f; } v; v.u = ((unsigned)u) << 16;
    return v.f;
}

// K0: weight bf16-transpose + in-degree histogram. (node_score/attn_b are
// DEAD: per-segment softmax is shift-invariant, the per-dst constant cancels.)
__global__ __launch_bounds__(256) void k_pre(
    const float* __restrict__ W1, const float* __restrict__ W2,
    const float* __restrict__ evW, const int* __restrict__ dst_idx,
    int* __restrict__ count,
    ushort* __restrict__ W1t, ushort* __restrict__ W2t, ushort* __restrict__ evWt)
{
    const int gid = blockIdx.x * 256 + threadIdx.x;   // grid 2500 -> gid < NE
    if (gid < 16384) {
        const int n = gid >> 7, k = gid & 127;
        W1t[gid] = (ushort)f2bf(W1[k * 128 + n]);
        W2t[gid] = (ushort)f2bf(W2[k * 128 + n]);
        if (gid < 8192) {
            const int n2 = gid >> 6, k2 = gid & 63;
            evWt[gid] = (ushort)f2bf(evW[k2 * 128 + n2]);
        }
    }
    atomicAdd(&count[dst_idx[gid]], 1);               // 2500*256 == NE exactly
}

// Scan A: per-block sums
__global__ __launch_bounds__(256) void k_scan_bsum(
    const int* __restrict__ count, int* __restrict__ bsum)
{
    __shared__ int s[256];
    const int t = threadIdx.x, i = blockIdx.x * 256 + t;
    s[t] = (i < NN) ? count[i] : 0;
    __syncthreads();
    for (int off = 128; off; off >>= 1) { if (t < off) s[t] += s[t + off]; __syncthreads(); }
    if (t == 0) bsum[blockIdx.x] = s[0];
}

// Scan B: serial scan of block sums
__global__ void k_scan_serial(const int* __restrict__ bsum, int* __restrict__ boff,
                              int* __restrict__ rowptr)
{
    if (blockIdx.x == 0 && threadIdx.x == 0) {
        int run = 0;
        for (int b = 0; b < NB_SCAN; ++b) { boff[b] = run; run += bsum[b]; }
        rowptr[NN] = run;   // == NE
    }
}

// Scan C: in-block exclusive scan
__global__ __launch_bounds__(256) void k_scan_final(
    const int* __restrict__ count, const int* __restrict__ boff,
    int* __restrict__ rowptr)
{
    __shared__ int s[256];
    const int t = threadIdx.x, i = blockIdx.x * 256 + t;
    const int v = (i < NN) ? count[i] : 0;
    s[t] = v;
    __syncthreads();
    for (int off = 1; off < 256; off <<= 1) {
        const int x = (t >= off) ? s[t - off] : 0;
        __syncthreads();
        s[t] += x;
        __syncthreads();
    }
    if (i < NN) rowptr[i] = boff[blockIdx.x] + s[t] - v;
}

// K2: CSR slot per edge (atomic isolated here; fire-and-forget store)
__global__ __launch_bounds__(256) void k_pos(
    const int* __restrict__ dst_idx, const int* __restrict__ rowptr,
    int* cursor, int* __restrict__ ipos)
{
    const int e = blockIdx.x * 256 + threadIdx.x;     // grid 2500 exact
    const int dd = dst_idx[e];
    ipos[e] = rowptr[dd] + atomicAdd(&cursor[dd], 1);
}

// K3: streaming scatter: score + bf16 row -> CSR slot. No atomics.
// 16-lane group x exactly 8 edges, fully unrolled -> 8 independent pipelines.
__global__ __launch_bounds__(256) void k_scatter(
    const float* __restrict__ ef, const float* __restrict__ attn_W,
    const int* __restrict__ ipos,
    float* __restrict__ s_srt, ushort* __restrict__ ef_srt)
{
    const int t   = threadIdx.x;
    const int sl  = t & 15;
    const int grp = blockIdx.x * 16 + (t >> 4);   // 5000*16 = 80000 groups
    const int e0  = grp * 8;                      // 80000*8 = NE exactly

    float4 wl;   // mean_h attn_W rows 128+sl*4 .. +3
    {
        const float4 r0 = *reinterpret_cast<const float4*>(attn_W + (128 + sl * 4 + 0) * 4);
        const float4 r1 = *reinterpret_cast<const float4*>(attn_W + (128 + sl * 4 + 1) * 4);
        const float4 r2 = *reinterpret_cast<const float4*>(attn_W + (128 + sl * 4 + 2) * 4);
        const float4 r3 = *reinterpret_cast<const float4*>(attn_W + (128 + sl * 4 + 3) * 4);
        wl.x = 0.25f * (r0.x + r0.y + r0.z + r0.w);
        wl.y = 0.25f * (r1.x + r1.y + r1.z + r1.w);
        wl.z = 0.25f * (r2.x + r2.y + r2.z + r2.w);
        wl.w = 0.25f * (r3.x + r3.y + r3.z + r3.w);
    }

    float4 v[8];
    int pos[8];
    #pragma unroll
    for (int j = 0; j < 8; ++j) {
        v[j]   = *reinterpret_cast<const float4*>(ef + (size_t)(e0 + j) * 64 + sl * 4);
        pos[j] = ipos[e0 + j];                    // same addr across 16 lanes: broadcast
    }
    #pragma unroll
    for (int j = 0; j < 8; ++j) {
        float s = v[j].x * wl.x + v[j].y * wl.y + v[j].z * wl.z + v[j].w * wl.w;
        #pragma unroll
        for (int off = 8; off; off >>= 1) s += __shfl_xor(s, off, 16);
        if (sl == 0) s_srt[pos[j]] = s;
        ushort4v o;
        o[0] = (ushort)f2bf(v[j].x); o[1] = (ushort)f2bf(v[j].y);
        o[2] = (ushort)f2bf(v[j].z); o[3] = (ushort)f2bf(v[j].w);
        *reinterpret_cast<ushort4v*>(ef_srt + (size_t)pos[j] * 64 + sl * 4) = o;
    }
}

// K4: per-node softmax+aggregate over CONTIGUOUS sorted segments.
__global__ __launch_bounds__(256) void k_agg_stream(
    const float* __restrict__ s_srt, const ushort* __restrict__ ef_srt,
    const int* __restrict__ rowptr, ushort* __restrict__ agg,
    float* __restrict__ msum)
{
    const int t  = threadIdx.x;
    const int sl = t & 15;
    const int n  = blockIdx.x * 16 + (t >> 4);   // grid 6250 -> exact
    const int beg = rowptr[n], end = rowptr[n + 1];

    float m = -3.0e38f;
    for (int i = beg + sl; i < end; i += 16)
        m = fmaxf(m, s_srt[i]);
    #pragma unroll
    for (int off = 8; off; off >>= 1)
        m = fmaxf(m, __shfl_xor(m, off, 16));

    f32x4 acc = {0.f, 0.f, 0.f, 0.f};
    float se = 0.f;
    int i = beg;
    for (; i + 2 <= end; i += 2) {
        const float s0 = s_srt[i], s1 = s_srt[i + 1];
        const ushort4v r0 = *reinterpret_cast<const ushort4v*>(ef_srt + (size_t)i * 64 + sl * 4);
        const ushort4v r1 = *reinterpret_cast<const ushort4v*>(ef_srt + (size_t)(i + 1) * 64 + sl * 4);
        const float e0 = expf(s0 - m), e1 = expf(s1 - m);
        acc[0] = fmaf(e0, bf2f(r0[0]), acc[0]); acc[1] = fmaf(e0, bf2f(r0[1]), acc[1]);
        acc[2] = fmaf(e0, bf2f(r0[2]), acc[2]); acc[3] = fmaf(e0, bf2f(r0[3]), acc[3]);
        acc[0] = fmaf(e1, bf2f(r1[0]), acc[0]); acc[1] = fmaf(e1, bf2f(r1[1]), acc[1]);
        acc[2] = fmaf(e1, bf2f(r1[2]), acc[2]); acc[3] = fmaf(e1, bf2f(r1[3]), acc[3]);
        se += e0 + e1;
    }
    for (; i < end; ++i) {
        const float s0 = s_srt[i];
        const ushort4v r0 = *reinterpret_cast<const ushort4v*>(ef_srt + (size_t)i * 64 + sl * 4);
        const float e0 = expf(s0 - m);
        acc[0] = fmaf(e0, bf2f(r0[0]), acc[0]); acc[1] = fmaf(e0, bf2f(r0[1]), acc[1]);
        acc[2] = fmaf(e0, bf2f(r0[2]), acc[2]); acc[3] = fmaf(e0, bf2f(r0[3]), acc[3]);
        se += e0;
    }

    ushort4v o;
    o[0] = (ushort)f2bf(acc[0]); o[1] = (ushort)f2bf(acc[1]);
    o[2] = (ushort)f2bf(acc[2]); o[3] = (ushort)f2bf(acc[3]);
    *reinterpret_cast<ushort4v*>(agg + (size_t)n * 64 + sl * 4) = o;
    if (sl == 0) msum[n] = se;
}

// K5: msg = (agg@evW)/(se+eps) + se/(se+eps)*evb ; out = nf + relu(msg@W1+b1)@W2 + b2
__global__ __launch_bounds__(256) void k_mega(
    const ushort* __restrict__ agg, const float* __restrict__ msum,
    const ushort* __restrict__ evWt, const float* __restrict__ evb,
    const ushort* __restrict__ W1t, const float* __restrict__ b1,
    const ushort* __restrict__ W2t, const float* __restrict__ b2,
    const float* __restrict__ nf, float* __restrict__ out)
{
    __shared__ ushort tls[4][16][136];
    const int wid  = threadIdx.x >> 6;
    const int lane = threadIdx.x & 63;
    const int n0   = blockIdx.x * 64 + wid * 16;
    if (n0 >= NN) return;
    const int r = lane & 15;
    const int g = lane >> 4;

    short8 aev0 = *reinterpret_cast<const short8*>(agg + (size_t)(n0 + r) * 64 + g * 8);
    short8 aev1 = *reinterpret_cast<const short8*>(agg + (size_t)(n0 + r) * 64 + 32 + g * 8);
    float cf[4], cb[4];
    #pragma unroll
    for (int i = 0; i < 4; ++i) {
        const float s = msum[n0 + g * 4 + i];
        const float c = 1.f / (s + 1e-6f);
        cf[i] = c; cb[i] = s * c;
    }
    #pragma unroll
    for (int nt = 0; nt < 8; ++nt) {
        f32x4 acc = {0.f, 0.f, 0.f, 0.f};
        const short8 b0 = *reinterpret_cast<const short8*>(evWt + (nt * 16 + r) * 64 + g * 8);
        const short8 bq = *reinterpret_cast<const short8*>(evWt + (nt * 16 + r) * 64 + 32 + g * 8);
        acc = __builtin_amdgcn_mfma_f32_16x16x32_bf16(aev0, b0, acc, 0, 0, 0);
        acc = __builtin_amdgcn_mfma_f32_16x16x32_bf16(aev1, bq, acc, 0, 0, 0);
        const float eb = evb[nt * 16 + r];
        #pragma unroll
        for (int i = 0; i < 4; ++i)
            tls[wid][g * 4 + i][nt * 16 + r] = (ushort)f2bf(acc[i] * cf[i] + cb[i] * eb);
    }
    asm volatile("s_waitcnt lgkmcnt(0)" ::: "memory");

    short8 a1[4];
    #pragma unroll
    for (int t = 0; t < 4; ++t)
        a1[t] = *reinterpret_cast<const short8*>(&tls[wid][r][t * 32 + g * 8]);
    asm volatile("s_waitcnt lgkmcnt(0)" ::: "memory");
    #pragma unroll
    for (int nt = 0; nt < 8; ++nt) {
        f32x4 acc = {0.f, 0.f, 0.f, 0.f};
        #pragma unroll
        for (int t = 0; t < 4; ++t) {
            const short8 b = *reinterpret_cast<const short8*>(
                W1t + (size_t)(nt * 16 + r) * 128 + t * 32 + g * 8);
            acc = __builtin_amdgcn_mfma_f32_16x16x32_bf16(a1[t], b, acc, 0, 0, 0);
        }
        const float bias = b1[nt * 16 + r];
        #pragma unroll
        for (int i = 0; i < 4; ++i)
            tls[wid][g * 4 + i][nt * 16 + r] = (ushort)f2bf(fmaxf(acc[i] + bias, 0.f));
    }
    asm volatile("s_waitcnt lgkmcnt(0)" ::: "memory");

    short8 a2[4];
    #pragma unroll
    for (int t = 0; t < 4; ++t)
        a2[t] = *reinterpret_cast<const short8*>(&tls[wid][r][t * 32 + g * 8]);
    #pragma unroll
    for (int nt = 0; nt < 8; ++nt) {
        f32x4 acc = {0.f, 0.f, 0.f, 0.f};
        #pragma unroll
        for (int t = 0; t < 4; ++t) {
            const short8 b = *reinterpret_cast<const short8*>(
                W2t + (size_t)(nt * 16 + r) * 128 + t * 32 + g * 8);
            acc = __builtin_amdgcn_mfma_f32_16x16x32_bf16(a2[t], b, acc, 0, 0, 0);
        }
        const float bias = b2[nt * 16 + r];
        #pragma unroll
        for (int i = 0; i < 4; ++i) {
            const size_t idx = (size_t)(n0 + g * 4 + i) * 128 + nt * 16 + r;
            out[idx] = nf[idx] + acc[i] + bias;
        }
    }
}

extern "C" void kernel_launch(void* const* d_in, const int* in_sizes, int n_in,
                              void* d_out, int out_size, void* d_ws, size_t ws_size,
                              hipStream_t stream)
{
    const float* nf     = (const float*)d_in[0];
    const float* ef     = (const float*)d_in[1];
    const float* attn_W = (const float*)d_in[2];
    const float* evW    = (const float*)d_in[4];
    const float* evb    = (const float*)d_in[5];
    const float* W1     = (const float*)d_in[6];
    const float* b1     = (const float*)d_in[7];
    const float* W2     = (const float*)d_in[8];
    const float* b2     = (const float*)d_in[9];
    const int*   eidx   = (const int*)d_in[10];
    const int*   dst    = eidx + NE;
    float* out = (float*)d_out;

    char* ws = (char*)d_ws;
    int*    count  = (int*)   (ws + 0);          //   400,000
    int*    cursor = (int*)   (ws + 400000);     //   400,000
    int*    rowptr = (int*)   (ws + 800000);     //   400,004 (pad -> 1,200,128)
    float*  msum   = (float*) (ws + 1200128);    //   400,000
    float*  s_srt  = (float*) (ws + 1600128);    // 2,560,000
    ushort* agg    = (ushort*)(ws + 4160128);    // 12,800,000
    int*    ipos   = (int*)   (ws + 4160128);    // 2,560,000 ALIAS of agg:
                                                 //   ipos dead before agg written
    ushort* W1t    = (ushort*)(ws + 16960128);   //    32,768
    ushort* W2t    = (ushort*)(ws + 16992896);   //    32,768
    ushort* evWt   = (ushort*)(ws + 17025664);   //    16,384
    int*    bsum   = (int*)   (ws + 17042048);   //     1,664
    int*    boff   = (int*)   (ws + 17043712);   //     1,664
    ushort* ef_srt = (ushort*)(ws + 17045376);   // 81,920,000 (total 98.97 MB,
                                                 //  < R5's proven 99.37 MB)

    hipMemsetAsync(count, 0, 800000, stream);    // count + cursor

    k_pre        <<<2500, 256, 0, stream>>>(W1, W2, evW, dst, count, W1t, W2t, evWt);
    k_scan_bsum  <<<NB_SCAN, 256, 0, stream>>>(count, bsum);
    k_scan_serial<<<1,    64,  0, stream>>>(bsum, boff, rowptr);
    k_scan_final <<<NB_SCAN, 256, 0, stream>>>(count, boff, rowptr);
    k_pos        <<<2500, 256, 0, stream>>>(dst, rowptr, cursor, ipos);
    k_scatter    <<<5000, 256, 0, stream>>>(ef, attn_W, ipos, s_srt, ef_srt);
    k_agg_stream <<<6250, 256, 0, stream>>>(s_srt, ef_srt, rowptr, agg, msum);
    k_mega       <<<1563, 256, 0, stream>>>(agg, msum, evWt, evb, W1t, b1, W2t, b2, nf, out);
}

// Round 7
// 195.450 us; speedup vs baseline: 4.4144x; 1.1543x over previous
//
#include <hip/hip_runtime.h>
#include <cstddef>

#define NN 100000
#define NE 640000
#define NB_SCAN 391   // ceil(NN/256)

typedef short  short8   __attribute__((ext_vector_type(8)));
typedef float  f32x4    __attribute__((ext_vector_type(4)));
typedef ushort ushort4v __attribute__((ext_vector_type(4)));

__device__ __forceinline__ short f2bf(float f) {   // RNE f32->bf16
    union { float f; unsigned u; } v; v.f = f;
    unsigned r = (v.u + 0x7fffu + ((v.u >> 16) & 1u)) >> 16;
    return (short)r;
}

// K0: weight bf16-transpose + in-degree histogram. (node_score/attn_b are
// DEAD: per-segment softmax is shift-invariant, the per-dst constant cancels —
// validated by R6 passing with absmax 0.031.)
__global__ __launch_bounds__(256) void k_pre(
    const float* __restrict__ W1, const float* __restrict__ W2,
    const float* __restrict__ evW, const int* __restrict__ dst_idx,
    int* __restrict__ count,
    ushort* __restrict__ W1t, ushort* __restrict__ W2t, ushort* __restrict__ evWt)
{
    const int gid = blockIdx.x * 256 + threadIdx.x;   // grid 2500 -> gid < NE
    if (gid < 16384) {
        const int n = gid >> 7, k = gid & 127;
        W1t[gid] = (ushort)f2bf(W1[k * 128 + n]);
        W2t[gid] = (ushort)f2bf(W2[k * 128 + n]);
        if (gid < 8192) {
            const int n2 = gid >> 6, k2 = gid & 63;
            evWt[gid] = (ushort)f2bf(evW[k2 * 128 + n2]);
        }
    }
    atomicAdd(&count[dst_idx[gid]], 1);               // 2500*256 == NE exactly
}

// Scan A: per-block sums
__global__ __launch_bounds__(256) void k_scan_bsum(
    const int* __restrict__ count, int* __restrict__ bsum)
{
    __shared__ int s[256];
    const int t = threadIdx.x, i = blockIdx.x * 256 + t;
    s[t] = (i < NN) ? count[i] : 0;
    __syncthreads();
    for (int off = 128; off; off >>= 1) { if (t < off) s[t] += s[t + off]; __syncthreads(); }
    if (t == 0) bsum[blockIdx.x] = s[0];
}

// Scan B (merged serial+final): each block self-computes its prefix over bsum
// (391 ints, L2-hot), then in-block exclusive scan -> rowptr. Last block
// writes rowptr[NN] = NE.
__global__ __launch_bounds__(256) void k_scan_final(
    const int* __restrict__ count, const int* __restrict__ bsum,
    int* __restrict__ rowptr)
{
    __shared__ int s[256];
    __shared__ int red[4];
    const int t = threadIdx.x, i = blockIdx.x * 256 + t;
    const int v = (i < NN) ? count[i] : 0;
    s[t] = v;

    int part = 0;
    for (int b = t; b < blockIdx.x; b += 256) part += bsum[b];
    #pragma unroll
    for (int off = 32; off; off >>= 1) part += __shfl_xor(part, off);
    if ((t & 63) == 0) red[t >> 6] = part;
    __syncthreads();
    const int boff = red[0] + red[1] + red[2] + red[3];

    for (int off = 1; off < 256; off <<= 1) {
        const int x = (t >= off) ? s[t - off] : 0;
        __syncthreads();
        s[t] += x;
        __syncthreads();
    }
    if (i < NN) rowptr[i] = boff + s[t] - v;
    if (blockIdx.x == NB_SCAN - 1 && t == 255) rowptr[NN] = boff + s[255];
}

// K2: build permutation grouping edges by dst (CSR)
__global__ __launch_bounds__(256) void k_permute(
    const int* __restrict__ dst_idx, const int* __restrict__ rowptr,
    int* cursor, int* __restrict__ perm)
{
    const int e = blockIdx.x * 256 + threadIdx.x;     // grid 2500 exact
    const int dd = dst_idx[e];
    perm[rowptr[dd] + atomicAdd(&cursor[dd], 1)] = e;
}

// K3: single-pass gather + ONLINE segment softmax + aggregation.
// 16-lane group per node; 8-deep batched independent loads (perm then ef rows)
// -> BW-bound, not latency-bound. Pad lanes get s=-3e38 -> weight exp()=0.
// Rows stay in registers between score and accumulate: ef is read ONCE.
__global__ __launch_bounds__(256) void k_agg_gather(
    const float* __restrict__ ef, const float* __restrict__ attn_W,
    const int* __restrict__ perm, const int* __restrict__ rowptr,
    ushort* __restrict__ agg, float* __restrict__ msum)
{
    const int t  = threadIdx.x;
    const int sl = t & 15;
    const int n  = blockIdx.x * 16 + (t >> 4);   // grid 6250 -> exact
    const int beg = rowptr[n], end = rowptr[n + 1];

    float4 wl;   // mean_h attn_W rows 128+sl*4 .. +3
    {
        const float4 r0 = *reinterpret_cast<const float4*>(attn_W + (128 + sl * 4 + 0) * 4);
        const float4 r1 = *reinterpret_cast<const float4*>(attn_W + (128 + sl * 4 + 1) * 4);
        const float4 r2 = *reinterpret_cast<const float4*>(attn_W + (128 + sl * 4 + 2) * 4);
        const float4 r3 = *reinterpret_cast<const float4*>(attn_W + (128 + sl * 4 + 3) * 4);
        wl.x = 0.25f * (r0.x + r0.y + r0.z + r0.w);
        wl.y = 0.25f * (r1.x + r1.y + r1.z + r1.w);
        wl.z = 0.25f * (r2.x + r2.y + r2.z + r2.w);
        wl.w = 0.25f * (r3.x + r3.y + r3.z + r3.w);
    }

    float m  = -3.0e38f;
    float se = 0.f;
    f32x4 acc = {0.f, 0.f, 0.f, 0.f};

    for (int i = beg; i < end; i += 8) {
        int pe[8];
        #pragma unroll
        for (int j = 0; j < 8; ++j)
            pe[j] = perm[(i + j < end) ? (i + j) : beg];   // dup is harmless
        float4 v[8];
        #pragma unroll
        for (int j = 0; j < 8; ++j)
            v[j] = *reinterpret_cast<const float4*>(ef + (size_t)pe[j] * 64 + sl * 4);
        float sc[8];
        #pragma unroll
        for (int j = 0; j < 8; ++j) {
            float x = v[j].x * wl.x + v[j].y * wl.y + v[j].z * wl.z + v[j].w * wl.w;
            #pragma unroll
            for (int off = 8; off; off >>= 1) x += __shfl_xor(x, off, 16);
            sc[j] = (i + j < end) ? x : -3.0e38f;          // pad -> weight 0
        }
        float bm = m;
        #pragma unroll
        for (int j = 0; j < 8; ++j) bm = fmaxf(bm, sc[j]);
        const float r = __expf(m - bm);    // first batch: exp(-inf)=0, acc/se are 0
        acc[0] *= r; acc[1] *= r; acc[2] *= r; acc[3] *= r; se *= r;
        m = bm;
        #pragma unroll
        for (int j = 0; j < 8; ++j) {
            const float w = __expf(sc[j] - m);
            acc[0] = fmaf(w, v[j].x, acc[0]);
            acc[1] = fmaf(w, v[j].y, acc[1]);
            acc[2] = fmaf(w, v[j].z, acc[2]);
            acc[3] = fmaf(w, v[j].w, acc[3]);
            se += w;
        }
    }

    ushort4v o;
    o[0] = (ushort)f2bf(acc[0]); o[1] = (ushort)f2bf(acc[1]);
    o[2] = (ushort)f2bf(acc[2]); o[3] = (ushort)f2bf(acc[3]);
    *reinterpret_cast<ushort4v*>(agg + (size_t)n * 64 + sl * 4) = o;
    if (sl == 0) msum[n] = se;
}

// K5: msg = (agg@evW)/(se+eps) + se/(se+eps)*evb ; out = nf + relu(msg@W1+b1)@W2 + b2
__global__ __launch_bounds__(256) void k_mega(
    const ushort* __restrict__ agg, const float* __restrict__ msum,
    const ushort* __restrict__ evWt, const float* __restrict__ evb,
    const ushort* __restrict__ W1t, const float* __restrict__ b1,
    const ushort* __restrict__ W2t, const float* __restrict__ b2,
    const float* __restrict__ nf, float* __restrict__ out)
{
    __shared__ ushort tls[4][16][136];
    const int wid  = threadIdx.x >> 6;
    const int lane = threadIdx.x & 63;
    const int n0   = blockIdx.x * 64 + wid * 16;
    if (n0 >= NN) return;
    const int r = lane & 15;
    const int g = lane >> 4;

    short8 aev0 = *reinterpret_cast<const short8*>(agg + (size_t)(n0 + r) * 64 + g * 8);
    short8 aev1 = *reinterpret_cast<const short8*>(agg + (size_t)(n0 + r) * 64 + 32 + g * 8);
    float cf[4], cb[4];
    #pragma unroll
    for (int i = 0; i < 4; ++i) {
        const float s = msum[n0 + g * 4 + i];
        const float c = 1.f / (s + 1e-6f);
        cf[i] = c; cb[i] = s * c;
    }
    #pragma unroll
    for (int nt = 0; nt < 8; ++nt) {
        f32x4 acc = {0.f, 0.f, 0.f, 0.f};
        const short8 b0 = *reinterpret_cast<const short8*>(evWt + (nt * 16 + r) * 64 + g * 8);
        const short8 bq = *reinterpret_cast<const short8*>(evWt + (nt * 16 + r) * 64 + 32 + g * 8);
        acc = __builtin_amdgcn_mfma_f32_16x16x32_bf16(aev0, b0, acc, 0, 0, 0);
        acc = __builtin_amdgcn_mfma_f32_16x16x32_bf16(aev1, bq, acc, 0, 0, 0);
        const float eb = evb[nt * 16 + r];
        #pragma unroll
        for (int i = 0; i < 4; ++i)
            tls[wid][g * 4 + i][nt * 16 + r] = (ushort)f2bf(acc[i] * cf[i] + cb[i] * eb);
    }
    asm volatile("s_waitcnt lgkmcnt(0)" ::: "memory");

    short8 a1[4];
    #pragma unroll
    for (int t = 0; t < 4; ++t)
        a1[t] = *reinterpret_cast<const short8*>(&tls[wid][r][t * 32 + g * 8]);
    asm volatile("s_waitcnt lgkmcnt(0)" ::: "memory");
    #pragma unroll
    for (int nt = 0; nt < 8; ++nt) {
        f32x4 acc = {0.f, 0.f, 0.f, 0.f};
        #pragma unroll
        for (int t = 0; t < 4; ++t) {
            const short8 b = *reinterpret_cast<const short8*>(
                W1t + (size_t)(nt * 16 + r) * 128 + t * 32 + g * 8);
            acc = __builtin_amdgcn_mfma_f32_16x16x32_bf16(a1[t], b, acc, 0, 0, 0);
        }
        const float bias = b1[nt * 16 + r];
        #pragma unroll
        for (int i = 0; i < 4; ++i)
            tls[wid][g * 4 + i][nt * 16 + r] = (ushort)f2bf(fmaxf(acc[i] + bias, 0.f));
    }
    asm volatile("s_waitcnt lgkmcnt(0)" ::: "memory");

    short8 a2[4];
    #pragma unroll
    for (int t = 0; t < 4; ++t)
        a2[t] = *reinterpret_cast<const short8*>(&tls[wid][r][t * 32 + g * 8]);
    #pragma unroll
    for (int nt = 0; nt < 8; ++nt) {
        f32x4 acc = {0.f, 0.f, 0.f, 0.f};
        #pragma unroll
        for (int t = 0; t < 4; ++t) {
            const short8 b = *reinterpret_cast<const short8*>(
                W2t + (size_t)(nt * 16 + r) * 128 + t * 32 + g * 8);
            acc = __builtin_amdgcn_mfma_f32_16x16x32_bf16(a2[t], b, acc, 0, 0, 0);
        }
        const float bias = b2[nt * 16 + r];
        #pragma unroll
        for (int i = 0; i < 4; ++i) {
            const size_t idx = (size_t)(n0 + g * 4 + i) * 128 + nt * 16 + r;
            out[idx] = nf[idx] + acc[i] + bias;
        }
    }
}

extern "C" void kernel_launch(void* const* d_in, const int* in_sizes, int n_in,
                              void* d_out, int out_size, void* d_ws, size_t ws_size,
                              hipStream_t stream)
{
    const float* nf     = (const float*)d_in[0];
    const float* ef     = (const float*)d_in[1];
    const float* attn_W = (const float*)d_in[2];
    const float* evW    = (const float*)d_in[4];
    const float* evb    = (const float*)d_in[5];
    const float* W1     = (const float*)d_in[6];
    const float* b1     = (const float*)d_in[7];
    const float* W2     = (const float*)d_in[8];
    const float* b2     = (const float*)d_in[9];
    const int*   eidx   = (const int*)d_in[10];
    const int*   dst    = eidx + NE;
    float* out = (float*)d_out;

    char* ws = (char*)d_ws;
    int*    count  = (int*)   (ws + 0);          //   400,000
    int*    cursor = (int*)   (ws + 400000);     //   400,000
    int*    rowptr = (int*)   (ws + 800000);     //   400,004 (pad -> 1,200,128)
    float*  msum   = (float*) (ws + 1200128);    //   400,000
    int*    perm   = (int*)   (ws + 1600128);    // 2,560,000
    ushort* agg    = (ushort*)(ws + 4160128);    // 12,800,000
    ushort* W1t    = (ushort*)(ws + 16960128);   //    32,768
    ushort* W2t    = (ushort*)(ws + 16992896);   //    32,768
    ushort* evWt   = (ushort*)(ws + 17025664);   //    16,384
    int*    bsum   = (int*)   (ws + 17042048);   //     1,664  (total ~17.0 MB)

    hipMemsetAsync(count, 0, 800000, stream);    // count + cursor

    k_pre        <<<2500, 256, 0, stream>>>(W1, W2, evW, dst, count, W1t, W2t, evWt);
    k_scan_bsum  <<<NB_SCAN, 256, 0, stream>>>(count, bsum);
    k_scan_final <<<NB_SCAN, 256, 0, stream>>>(count, bsum, rowptr);
    k_permute    <<<2500, 256, 0, stream>>>(dst, rowptr, cursor, perm);
    k_agg_gather <<<6250, 256, 0, stream>>>(ef, attn_W, perm, rowptr, agg, msum);
    k_mega       <<<1563, 256, 0, stream>>>(agg, msum, evWt, evb, W1t, b1, W2t, b2, nf, out);
}